// Round 11
// baseline (331.491 us; speedup 1.0000x reference)
//
#include <hip/hip_runtime.h>
#include <hip/hip_bf16.h>

#define HH 128
#define WW 128
#define BB 4
#define NPIX 16384            // HH*WW
#define EPSV 1e-5f

using bfrag = __attribute__((ext_vector_type(8))) short;     // 8 bf16 (4 VGPRs)
using f32x4 = __attribute__((ext_vector_type(4))) float;
using us8   = __attribute__((ext_vector_type(8))) unsigned short;

__device__ __forceinline__ float bf2f(ushort u) {
  union { unsigned int i; float f; } x; x.i = ((unsigned int)u) << 16; return x.f;
}
__device__ __forceinline__ ushort f2bf(float f) {
  union { float f; unsigned int i; } x; x.f = f;
  unsigned int r = x.i + 0x7fffu + ((x.i >> 16) & 1u);   // RNE
  return (ushort)(r >> 16);
}

#define GLOAD16(gsrc, ldst) \
  __builtin_amdgcn_global_load_lds( \
      (const __attribute__((address_space(1))) unsigned int*)(gsrc), \
      (__attribute__((address_space(3))) unsigned int*)(ldst), 16, 0, 0)

// ---------------------------------------------------------------------------
// Implicit-GEMM conv via MFMA — FAT-WAVE config: 256x256 block tile, 4 waves
// of 128x128 each (256 threads), BK=64.  Rationale: LDS-read redundancy is
// the wall (fragment re-reads across waves).  At 128x128/wave, per K-tile/CU
// LDS traffic = 128KB rd + 64KB wr = ~750cyc vs 620cyc MFMA -> bound ~83%
// (vs 62% at 8x(128x64), 41% at 128^2 tile).  Schedule = the R7 one proven
// to capture ~100% of its bound: ONE barrier per K-tile, prefetch-1,
// vmcnt(0) at loop top (loads had a full ~620-cyc compute phase to land).
// acc[8][8] f32x4 = 256 VGPR; __launch_bounds__(256,1) -> up to 512 VGPR.
// LDS: 2 x (A 32KB | B 32KB) = 128KB, 1 block/CU, grid 256 XCD-contig.
// EPI: 0 = relu->bf16 NCHW, 3 = relu->fp32 NCHW,
//      4 = dual-bias, relu, LDS-transposed store -> bf16 [b][p][256].
// ---------------------------------------------------------------------------
template<int CIN1, int TAPS1, int CIN2, int TAPS2, int EPI>
__global__ __launch_bounds__(256, 1)
void convgemm(const ushort* __restrict__ B1,    // [b][16384][CIN1] bf16
              const ushort* __restrict__ B2,    // [b][16384][CIN2] bf16 (opt)
              const ushort* __restrict__ wR,    // repacked weights (tiles)
              const float*  __restrict__ tb,    // bias per out-channel
              const float*  __restrict__ tb2,   // second bias (EPI 4)
              void*          __restrict__ outp,
              const ushort* __restrict__ zerop) // 256B of zeros
{
  __shared__ char ldsb[131072];                 // 2 x (A 32KB | B 32KB)
  constexpr int nch1 = CIN1 / 64;
  constexpr int nch2 = (CIN2 > 0) ? CIN2 / 64 : 0;
  constexpr int NCH  = TAPS1 * nch1 + TAPS2 * nch2;

  // grid 256: XCD g = bid&7 owns 32 contiguous nids (h-locality per L2)
  const int nid = (blockIdx.x & 7) * 32 + (blockIdx.x >> 3);
  const int b   = nid >> 6;
  const int h2  = (nid & 63) * 2;               // first of the two rows

  const int tid  = threadIdx.x;
  const int lane = tid & 63;
  const int wid  = tid >> 6;                    // 0..3
  const int m0   = (wid >> 1) * 128;            // M-wave half (128 outs)
  const int n0   = (wid & 1) * 128;             // N-wave half (128 px)

  f32x4 acc[8][8];
  #pragma unroll
  for (int i = 0; i < 8; ++i)
    #pragma unroll
    for (int j = 0; j < 8; ++j) acc[i][j] = (f32x4){0.f, 0.f, 0.f, 0.f};

  // B staging constants: 8 segs x 4KB; rowB = pixel 0..255, inv-swizzled k
  int ro1[8], ro2[8], w_[8], prow_[8];
  #pragma unroll
  for (int s = 0; s < 8; ++s) {
    const int boff = s * 4096 + tid * 16;
    const int rowB = boff >> 7;                 // 0..255
    prow_[s] = rowB >> 7;
    w_[s]    = rowB & 127;
    const int sl8 = (((tid & 7) ^ (rowB & 7)) << 3);
    ro1[s] = (prow_[s] * WW + w_[s]) * CIN1 + sl8;
    ro2[s] = (CIN2 > 0) ? rowB * CIN2 + sl8 : 0;
  }
  const size_t B1base = (size_t)b * NPIX * CIN1;
  const size_t B2base = (CIN2 > 0) ? (size_t)b * NPIX * CIN2 : 0;

  auto stage = [&](int t, int buf) {
    char* baseA = ldsb + buf * 65536;
    char* baseB = baseA + 32768;
    const char* wsrc = (const char*)(wR + (size_t)t * (256 * 64));
    #pragma unroll
    for (int i = 0; i < 8; ++i)                 // A: 8 loads, linear image
      GLOAD16(wsrc + i * 4096 + tid * 16, baseA + i * 4096 + tid * 16);
    if (CIN2 == 0 || t < TAPS1 * nch1) {
      const int tap = t / nch1, ch = t - tap * nch1;
      const int dy = (TAPS1 == 9) ? tap / 3 - 1 : 0;
      const int dx = (TAPS1 == 9) ? tap - (tap / 3) * 3 - 1 : 0;
      const int hy0 = h2 + dy;
      const bool oob0 = (hy0 < 0) | (hy0 > 127);
      const bool oob1 = (hy0 + 1 < 0) | (hy0 + 1 > 127);
      const int zr = (dx < 0) ? 0 : ((dx > 0) ? 127 : -1);
      const ushort* bch = B1 + B1base + (size_t)(hy0 * WW + dx) * CIN1 + ch * 64;
      #pragma unroll
      for (int s = 0; s < 8; ++s) {
        const bool bad = (prow_[s] ? oob1 : oob0) || (w_[s] == zr);
        const ushort* src = bad ? zerop : (bch + ro1[s]);
        GLOAD16(src, baseB + s * 4096 + tid * 16);
      }
    } else {
      const int ch = t - TAPS1 * nch1;
      const ushort* bch = B2 + B2base + (size_t)(h2 * WW) * CIN2 + ch * 64;
      #pragma unroll
      for (int s = 0; s < 8; ++s)
        GLOAD16(bch + ro2[s], baseB + s * 4096 + tid * 16);
    }
  };

  stage(0, 0);                                   // 16 loads in flight
  for (int t = 0; t < NCH; ++t) {
    asm volatile("s_waitcnt vmcnt(0)" ::: "memory"); // tile t retired (issued
                                                     // a full compute ago)
    __builtin_amdgcn_s_barrier();                // t's LDS valid block-wide;
                                                 // all waves done reading t-1
    __builtin_amdgcn_sched_barrier(0);           // no hoist above barrier
    if (t + 1 < NCH) stage(t + 1, (t + 1) & 1);  // overlap with compute(t)
    const char* cb = ldsb + (t & 1) * 65536;
    #pragma unroll
    for (int kc = 0; kc < 2; ++kc) {
      const int sw = ((((kc << 2) | (lane >> 4)) ^ (lane & 7)) << 4);
      bfrag af[8], bf[8];
      #pragma unroll
      for (int mf = 0; mf < 8; ++mf)
        af[mf] = *(const bfrag*)(cb + (m0 + mf * 16 + (lane & 15)) * 128 + sw);
      #pragma unroll
      for (int nf = 0; nf < 8; ++nf)
        bf[nf] = *(const bfrag*)(cb + 32768 +
                     (n0 + nf * 16 + (lane & 15)) * 128 + sw);
      __builtin_amdgcn_s_setprio(1);
      #pragma unroll
      for (int mf = 0; mf < 8; ++mf)
        #pragma unroll
        for (int nf = 0; nf < 8; ++nf)
          acc[mf][nf] = __builtin_amdgcn_mfma_f32_16x16x32_bf16(
              af[mf], bf[nf], acc[mf][nf], 0, 0, 0);
      __builtin_amdgcn_s_setprio(0);
    }
  }

  if (EPI == 4) {
    // dual bias + relu; transpose via LDS in two 128-pixel passes
    ushort* ct = (ushort*)ldsb;                  // [128 px][264] per pass
    #pragma unroll
    for (int ph = 0; ph < 2; ++ph) {
      __syncthreads();
      if ((wid & 1) == ph) {                     // waves owning px half ph
        #pragma unroll
        for (int mf = 0; mf < 8; ++mf) {
          #pragma unroll
          for (int r2 = 0; r2 < 4; ++r2) {
            const int o = m0 + mf * 16 + (lane >> 4) * 4 + r2;
            const float bias = tb[o] + tb2[o];
            #pragma unroll
            for (int nf = 0; nf < 8; ++nf)
              ct[(nf * 16 + (lane & 15)) * 264 + o] =
                  f2bf(fmaxf(acc[mf][nf][r2] + bias, 0.f));
          }
        }
      }
      __syncthreads();
      const int p  = tid >> 1;
      const int hf = tid & 1;
      ushort* dst = (ushort*)outp +
          ((size_t)b * NPIX + (h2 + ph) * WW + p) * 256 + hf * 128;
      const ushort* src = ct + p * 264 + hf * 128;
      #pragma unroll
      for (int j = 0; j < 16; ++j)
        *(us8*)(dst + j * 8) = *(const us8*)(src + j * 8);
    }
    return;
  }

  // EPI 0 / 3: C[o][px]; px = n0 + nf*16 + (lane&15) spans two image rows
  #pragma unroll
  for (int mf = 0; mf < 8; ++mf) {
    #pragma unroll
    for (int r2 = 0; r2 < 4; ++r2) {
      const int o = m0 + mf * 16 + (lane >> 4) * 4 + r2;
      const float bias = tb[o];
      #pragma unroll
      for (int nf = 0; nf < 8; ++nf) {
        const int px   = n0 + nf * 16 + (lane & 15);
        const int hout = h2 + (px >> 7);
        const int w    = px & 127;
        float v = fmaxf(acc[mf][nf][r2] + bias, 0.f);
        const size_t oi = (((size_t)(b * 256 + o)) << 14) + hout * WW + w;
        if (EPI == 0) ((ushort*)outp)[oi] = f2bf(v);
        else          ((float*)outp)[oi] = v;
      }
    }
  }
}

// ---------------------------------------------------------------------------
// fused weight repack: fold BN scale, bf16, swizzled LDS-image layout; emit tb.
// W is OIHW flat [COUT_local][CIN][TAPS]; tiles laid out cb + tap*nch + ch.
// ---------------------------------------------------------------------------
struct WSeg {
  const float *W, *g, *bb, *mm, *vv;
  ushort* dst; float* tb;
  int CIN, COUT, TAPS, o_off, cb, start, end;
};

__device__ __forceinline__ void wrepack_one(const WSeg& s, int e) {
  const int tap = e % s.TAPS;
  const int ci  = (e / s.TAPS) % s.CIN;
  const int o   = e / (s.TAPS * s.CIN);
  const int oi  = o + s.o_off;
  const float sc = s.g[o] * rsqrtf(s.vv[o] + EPSV);
  const int nch = s.CIN / 64;
  const int ch = ci >> 6, kl = ci & 63;
  const int slot = (kl >> 3) ^ (oi & 7);
  s.dst[(((size_t)((s.cb + tap * nch + ch) * s.COUT) + oi) << 6) +
        (slot << 3) + (kl & 7)] = f2bf(s.W[e] * sc);
  if (ci == 0 && tap == 0) s.tb[oi] = s.bb[o] - s.mm[o] * sc;
}

__global__ __launch_bounds__(256)
void wrepack_all(WSeg s0, WSeg s1, WSeg s2, WSeg s3, WSeg s4) {
  const int id = blockIdx.x * 256 + threadIdx.x;
  if (id < s0.end)      wrepack_one(s0, id - s0.start);
  else if (id < s1.end) wrepack_one(s1, id - s1.start);
  else if (id < s2.end) wrepack_one(s2, id - s2.start);
  else if (id < s3.end) wrepack_one(s3, id - s3.start);
  else if (id < s4.end) wrepack_one(s4, id - s4.start);
}

// ---------------------------------------------------------------------------
// x (fp32 NCHW) -> xT (bf16 [b][p][256]).  Thread = 4 px x 64 ch.
// ---------------------------------------------------------------------------
__global__ __launch_bounds__(256)
void repack_x(const float* __restrict__ x, ushort* __restrict__ xT)
{
  const int b  = blockIdx.z;
  const int cq = threadIdx.x >> 6;            // channel quarter
  const int pg = threadIdx.x & 63;
  const int p0 = blockIdx.x * 256 + pg * 4;
  const size_t xb = (size_t)b * 256 * NPIX;
  ushort* ob = xT + ((size_t)b * NPIX + p0) * 256 + cq * 64;
  for (int cc = 0; cc < 64; cc += 8) {
    us8 v[4];
    #pragma unroll
    for (int j = 0; j < 8; ++j) {
      const float4 q = *(const float4*)&x[xb + (size_t)(cq * 64 + cc + j) * NPIX + p0];
      v[0][j] = f2bf(q.x); v[1][j] = f2bf(q.y);
      v[2][j] = f2bf(q.z); v[3][j] = f2bf(q.w);
    }
    #pragma unroll
    for (int k = 0; k < 4; ++k)
      *(us8*)(ob + (size_t)k * 256 + cc) = v[k];
  }
}

// p12 (bf16 NCHW; c<128 = top-pooled, c>=128 = left-pooled)
//   -> sumT (bf16 [b][p][128]).  Thread = 4 px x 32 ch.
__global__ __launch_bounds__(256)
void sum_repack(const ushort* __restrict__ p12, ushort* __restrict__ sT)
{
  const int b  = blockIdx.z;
  const int cq = threadIdx.x >> 6;            // 32-channel chunk
  const int pg = threadIdx.x & 63;
  const int p0 = blockIdx.x * 256 + pg * 4;
  const size_t base = (size_t)b * 256 * NPIX;
  const ushort* P1 = p12 + base;
  const ushort* P2 = p12 + base + (size_t)128 * NPIX;
  ushort* ob = sT + ((size_t)b * NPIX + p0) * 128 + cq * 32;
  for (int cc = 0; cc < 32; cc += 8) {
    us8 v[4];
    #pragma unroll
    for (int j = 0; j < 8; ++j) {
      const size_t ci = (size_t)(cq * 32 + cc + j) * NPIX + p0;
      const ushort4 a = *(const ushort4*)&P1[ci];
      const ushort4 d = *(const ushort4*)&P2[ci];
      v[0][j] = f2bf(bf2f(a.x) + bf2f(d.x));
      v[1][j] = f2bf(bf2f(a.y) + bf2f(d.y));
      v[2][j] = f2bf(bf2f(a.z) + bf2f(d.z));
      v[3][j] = f2bf(bf2f(a.w) + bf2f(d.w));
    }
    #pragma unroll
    for (int k = 0; k < 4; ++k)
      *(us8*)(ob + (size_t)k * 128 + cc) = v[k];
  }
}

// merged pools, in place on p12 (bf16 [b][256][H][W]):
//  blocks 0..255:      reverse cummax along H on planes 0..127  (2 ch/block)
//  blocks 256..16639:  reverse cummax along W on planes 128..255 (4 rows/blk)
__global__ __launch_bounds__(256)
void scans(ushort* __restrict__ p)
{
  const int bid = blockIdx.x;
  if (bid < 256) {
    const int b = bid >> 6;
    const int c = (bid & 63) * 2 + (threadIdx.x >> 7);
    const int w = threadIdx.x & 127;
    ushort* base = p + ((size_t)(b * 256 + c)) * NPIX + w;
    float cur = bf2f(base[(HH - 1) * WW]);
    for (int hr = HH - 2; hr >= 0; --hr) {
      cur = fmaxf(cur, bf2f(base[hr * WW]));
      base[hr * WW] = f2bf(cur);
    }
  } else {
    const int lane = threadIdx.x & 63;
    const int rid  = (bid - 256) * 4 + (threadIdx.x >> 6); // b*128c*128h rows
    const int b = rid >> 14;
    const int rem = rid & 16383;
    const int c = rem >> 7, h = rem & 127;
    ushort* r = p + ((size_t)(b * 256 + 128 + c)) * NPIX + h * WW;
    const ushort2 u = ((const ushort2*)r)[lane];
    const float e0 = bf2f(u.x), e1 = bf2f(u.y);
    float m = fmaxf(e0, e1);
    #pragma unroll
    for (int off = 1; off < 64; off <<= 1) {
      const float o = __shfl_down(m, off, 64);
      if (lane + off < 64) m = fmaxf(m, o);
    }
    float s = __shfl_down(m, 1, 64);
    if (lane == 63) s = -3.4e38f;
    const float o1 = fmaxf(e1, s);
    const float o0 = fmaxf(e0, o1);
    ushort2 w2; w2.x = f2bf(o0); w2.y = f2bf(o1);
    ((ushort2*)r)[lane] = w2;
  }
}

// ---------------------------------------------------------------------------
extern "C" void kernel_launch(void* const* d_in, const int* in_sizes, int n_in,
                              void* d_out, int out_size, void* d_ws, size_t ws_size,
                              hipStream_t stream) {
  const float* x    = (const float*)d_in[0];
  const float* w_p1 = (const float*)d_in[1];
  const float* g_p1 = (const float*)d_in[2];
  const float* b_p1 = (const float*)d_in[3];
  const float* m_p1 = (const float*)d_in[4];
  const float* v_p1 = (const float*)d_in[5];
  const float* w_p2 = (const float*)d_in[6];
  const float* g_p2 = (const float*)d_in[7];
  const float* b_p2 = (const float*)d_in[8];
  const float* m_p2 = (const float*)d_in[9];
  const float* v_p2 = (const float*)d_in[10];
  const float* w_pc = (const float*)d_in[11];
  const float* g_pb = (const float*)d_in[12];
  const float* b_pb = (const float*)d_in[13];
  const float* m_pb = (const float*)d_in[14];
  const float* v_pb = (const float*)d_in[15];
  const float* w_c1 = (const float*)d_in[16];
  const float* g_b1 = (const float*)d_in[17];
  const float* b_b1 = (const float*)d_in[18];
  const float* m_b1 = (const float*)d_in[19];
  const float* v_b1 = (const float*)d_in[20];
  const float* w_c2 = (const float*)d_in[21];
  const float* g_c2 = (const float*)d_in[22];
  const float* b_c2 = (const float*)d_in[23];
  const float* m_c2 = (const float*)d_in[24];
  const float* v_c2 = (const float*)d_in[25];

  char* ws = (char*)d_ws;
  // arena (bytes):
  ushort* xT      = (ushort*)(ws + 0);           // 32MB [b][p][256]
  ushort* p12     = (ushort*)(ws + 33554432);    // 32MB bf16 NCHW (top|left)
  ushort* relu1T  = (ushort*)(ws + 33554432);    // 32MB alias p12 (dead after sum)
  ushort* sumT    = (ushort*)(ws + 67108864);    // 16MB [b][p][128]
  ushort* wR_p12  = (ushort*)(ws + 100663296);   // 36 tiles  (1179648 B)
  ushort* wR_pcc1 = (ushort*)(ws + 101842944);   // 22 tiles  (720896 B)
  ushort* wR_c2   = (ushort*)(ws + 102563840);   // 36 tiles  (1179648 B)
  float*  tb_p12  = (float*)(ws + 103743488);    // 1KB each
  float*  tb_pc   = (float*)(ws + 103744512);
  float*  tb_c1   = (float*)(ws + 103745536);
  float*  tb_c2   = (float*)(ws + 103746560);
  ushort* zerop   = (ushort*)(ws + 103747584);   // 256B zeros

  hipMemsetAsync(zerop, 0, 256, stream);

  // fused weight repack (fold BN scale; emit tb)
  const int n_p  = 128 * 256 * 9;    // 294912 (p1 and p2 each)
  const int n_pc = 256 * 128 * 9;    // 294912
  const int n_c1 = 256 * 256 * 1;    // 65536
  const int n_c2 = 256 * 256 * 9;    // 589824
  WSeg s0 = {w_p1, g_p1, b_p1, m_p1, v_p1, wR_p12, tb_p12, 256, 256, 9, 0, 0,
             0, n_p};
  WSeg s1 = {w_p2, g_p2, b_p2, m_p2, v_p2, wR_p12, tb_p12, 256, 256, 9, 128, 0,
             n_p, 2 * n_p};
  WSeg s2 = {w_pc, g_pb, b_pb, m_pb, v_pb, wR_pcc1, tb_pc, 128, 256, 9, 0, 0,
             2 * n_p, 2 * n_p + n_pc};
  WSeg s3 = {w_c1, g_b1, b_b1, m_b1, v_b1, wR_pcc1, tb_c1, 256, 256, 1, 0, 18,
             2 * n_p + n_pc, 2 * n_p + n_pc + n_c1};
  WSeg s4 = {w_c2, g_c2, b_c2, m_c2, v_c2, wR_c2, tb_c2, 256, 256, 9, 0, 0,
             2 * n_p + n_pc + n_c1, 2 * n_p + n_pc + n_c1 + n_c2};
  const int n_all = 2 * n_p + n_pc + n_c1 + n_c2;
  wrepack_all<<<dim3((n_all + 255) / 256), 256, 0, stream>>>(s0, s1, s2, s3, s4);

  // x -> xT
  repack_x<<<dim3(NPIX / 256, 1, BB), 256, 0, stream>>>(x, xT);

  // p12 = relu(bn(conv3x3(x, [w_p1;w_p2])))  (bf16 NCHW, 256 planes)
  convgemm<256, 9, 0, 0, 0><<<dim3(256), 256, 0, stream>>>(
      xT, nullptr, wR_p12, tb_p12, nullptr, p12, zerop);

  // pools (in place): top on planes 0-127, left on planes 128-255
  scans<<<dim3(256 + 16384), 256, 0, stream>>>(p12);

  // sumT = top + left, transposed bf16
  sum_repack<<<dim3(NPIX / 256, 1, BB), 256, 0, stream>>>(p12, sumT);

  // relu1T = relu(bn(conv3x3(sumT)) + bn(conv1x1(x))), bf16 [b][p][256]
  // (fused pc + c1; writes transposed directly; overwrites p12 region)
  convgemm<128, 9, 256, 1, 4><<<dim3(256), 256, 0, stream>>>(
      sumT, xT, wR_pcc1, tb_pc, tb_c1, relu1T, zerop);

  // out = relu(bn(conv3x3(relu1T))), fp32 NCHW
  convgemm<256, 9, 0, 0, 3><<<dim3(256), 256, 0, stream>>>(
      relu1T, nullptr, wR_c2, tb_c2, nullptr, (void*)d_out, zerop);
}

// Round 12
// 299.103 us; speedup vs baseline: 1.1083x; 1.1083x over previous
//
#include <hip/hip_runtime.h>
#include <hip/hip_bf16.h>

#define HH 128
#define WW 128
#define BB 4
#define NPIX 16384            // HH*WW
#define EPSV 1e-5f

using bfrag = __attribute__((ext_vector_type(8))) short;     // 8 bf16 (4 VGPRs)
using f32x4 = __attribute__((ext_vector_type(4))) float;
using us8   = __attribute__((ext_vector_type(8))) unsigned short;

__device__ __forceinline__ float bf2f(ushort u) {
  union { unsigned int i; float f; } x; x.i = ((unsigned int)u) << 16; return x.f;
}
__device__ __forceinline__ ushort f2bf(float f) {
  union { float f; unsigned int i; } x; x.f = f;
  unsigned int r = x.i + 0x7fffu + ((x.i >> 16) & 1u);   // RNE
  return (ushort)(r >> 16);
}

#define GLOAD16(gsrc, ldst) \
  __builtin_amdgcn_global_load_lds( \
      (const __attribute__((address_space(1))) unsigned int*)(gsrc), \
      (__attribute__((address_space(3))) unsigned int*)(ldst), 16, 0, 0)

// ---------------------------------------------------------------------------
// Implicit-GEMM conv via MFMA (R7 structure — best measured).  Double-buffered
// LDS, ONE barrier per K-tile:
//   vmcnt(0) [tile t loads, issued a full compute ago] -> s_barrier ->
//   ds_read all 16 frags of t -> issue stage(t+1) -> 32 MFMA.
// (reorder vs R7: frag ds_reads issue BEFORE staging VMEM so lgkm latency
// overlaps staging address-calc; MFMAs gate on lgkmcnt as before.)
// Tile: BM=128 outs x BN=128 px (one image row), 4 waves, wave=64x64.
// 64KB LDS -> 2 blocks/CU (cross-block overlap covers barrier bubbles).
// EPI: 0 = relu->bf16 NCHW, 3 = relu->fp32 NCHW,
//      4 = dual-bias, relu, LDS-transposed store -> bf16 [b][p][256].
// Grid: 1024 blocks 1D; XCD g owns h in [16g,16g+16) (L2 halo reuse).
// ---------------------------------------------------------------------------
template<int CIN1, int TAPS1, int CIN2, int TAPS2, int EPI>
__global__ __launch_bounds__(256, 2)
void convgemm(const ushort* __restrict__ B1,    // [b][16384][CIN1] bf16
              const ushort* __restrict__ B2,    // [b][16384][CIN2] bf16 (opt)
              const ushort* __restrict__ wR,    // repacked weights (tiles)
              const float*  __restrict__ tb,    // bias per out-channel
              const float*  __restrict__ tb2,   // second bias (EPI 4)
              void*          __restrict__ outp,
              const ushort* __restrict__ zerop) // 256B of zeros
{
  __shared__ ushort lds[2][16384];              // per buf: 16KB A | 16KB B
  constexpr int nch1 = CIN1 / 64;
  constexpr int nch2 = (CIN2 > 0) ? CIN2 / 64 : 0;
  constexpr int NCH  = TAPS1 * nch1 + TAPS2 * nch2;

  // XCD-locality decode: g = XCD, owns 16 consecutive h for all (b, o-tile)
  const int g  = blockIdx.x & 7;
  const int r  = blockIdx.x >> 3;               // 0..127
  const int bo = r >> 4;                        // b*2 + o
  const int h  = g * 16 + (r & 15);
  const int o_base = (bo & 1) * 128;
  const int b  = bo >> 1;

  const int tid  = threadIdx.x;
  const int lane = tid & 63;
  const int wid  = tid >> 6;
  const int m0 = (wid >> 1) * 64;
  const int n0 = (wid & 1) * 64;

  f32x4 acc[4][4];
  #pragma unroll
  for (int i = 0; i < 4; ++i)
    #pragma unroll
    for (int j = 0; j < 4; ++j) acc[i][j] = (f32x4){0.f, 0.f, 0.f, 0.f};

  // staging lane constants (B side): per segment, LDS pixel-row & k-offset
  int rowB[4], ro1[4], ro2[4];
  #pragma unroll
  for (int s = 0; s < 4; ++s) {
    const int boff = (wid * 4 + s) * 1024 + lane * 16;   // byte off in B image
    rowB[s] = boff >> 7;                                  // pixel row 0..127
    const int sl8 = ((((boff >> 4) & 7) ^ (rowB[s] & 7)) << 3);
    ro1[s] = rowB[s] * CIN1 + sl8;
    ro2[s] = (CIN2 > 0) ? rowB[s] * CIN2 + sl8 : 0;
  }
  const size_t B1base = (size_t)b * NPIX * CIN1;
  const size_t B2base = (CIN2 > 0) ? (size_t)b * NPIX * CIN2 : 0;

  auto stage = [&](int t, int buf) {
    char* base = (char*)&lds[buf][0];
    const ushort* wsrc = wR + ((size_t)t * 256 + o_base) * 64;
    const ushort* bch;
    int zr; bool oob, ph2;
    if (CIN2 == 0 || t < TAPS1 * nch1) {
      const int tap = t / nch1, ch = t - tap * nch1;
      const int dy = (TAPS1 == 9) ? tap / 3 - 1 : 0;
      const int dx = (TAPS1 == 9) ? tap - (tap / 3) * 3 - 1 : 0;
      const int hy = h + dy;
      oob = (hy < 0) | (hy >= HH);
      zr  = (dx < 0) ? 0 : ((dx > 0) ? 127 : -1);
      bch = B1 + B1base + (size_t)(hy * WW + dx) * CIN1 + ch * 64;
      ph2 = false;
    } else {
      const int ch = t - TAPS1 * nch1;
      oob = false; zr = -1;
      bch = B2 + B2base + (size_t)(h * WW) * CIN2 + ch * 64;
      ph2 = true;
    }
    #pragma unroll
    for (int s = 0; s < 4; ++s) {
      const int off = (wid * 4 + s) * 1024;               // bytes
      GLOAD16((const char*)wsrc + off + lane * 16, base + off);
      const int roff = ph2 ? ro2[s] : ro1[s];
      const ushort* bs = (oob || rowB[s] == zr) ? zerop : (bch + roff);
      GLOAD16(bs, base + 16384 + off);
    }
  };

  stage(0, 0);                                   // 8 loads in flight
  int cur = 0;
  for (int t = 0; t < NCH; ++t) {
    asm volatile("s_waitcnt vmcnt(0)" ::: "memory");  // tile t retired (issued
                                                      // a full compute ago)
    __builtin_amdgcn_s_barrier();                // t's LDS valid block-wide;
                                                 // all waves done reading t-1
    __builtin_amdgcn_sched_barrier(0);           // no hoist above barrier
    const char* base = (const char*)&lds[cur][0];
    bfrag af[2][4], bfv[2][4];                   // issue all frag ds_reads
    #pragma unroll
    for (int kc = 0; kc < 2; ++kc) {
      const int sw = ((((kc << 2) | (lane >> 4)) ^ (lane & 7)) << 4); // bytes
      #pragma unroll
      for (int mf = 0; mf < 4; ++mf)
        af[kc][mf] = *(const bfrag*)(base + (m0 + mf * 16 + (lane & 15)) * 128 + sw);
      #pragma unroll
      for (int nf = 0; nf < 4; ++nf)
        bfv[kc][nf] = *(const bfrag*)(base + 16384 + (n0 + nf * 16 + (lane & 15)) * 128 + sw);
    }
    if (t + 1 < NCH) stage(t + 1, cur ^ 1);      // VMEM issue under lgkm lat
    __builtin_amdgcn_s_setprio(1);
    #pragma unroll
    for (int kc = 0; kc < 2; ++kc)
      #pragma unroll
      for (int mf = 0; mf < 4; ++mf)
        #pragma unroll
        for (int nf = 0; nf < 4; ++nf)
          acc[mf][nf] = __builtin_amdgcn_mfma_f32_16x16x32_bf16(
              af[kc][mf], bfv[kc][nf], acc[mf][nf], 0, 0, 0);
    __builtin_amdgcn_s_setprio(0);
    cur ^= 1;
  }

  if (EPI == 4) {
    // dual bias + relu, transpose via LDS, store bf16 [b][p][256] rows
    __syncthreads();                             // all compute done, LDS free
    ushort* ct = (ushort*)&lds[0][0];            // [128 px][136] (pad 8)
    const int pl0 = n0 + (lane & 15);
    #pragma unroll
    for (int mf = 0; mf < 4; ++mf) {
      #pragma unroll
      for (int r2 = 0; r2 < 4; ++r2) {
        const int ol = m0 + mf * 16 + (lane >> 4) * 4 + r2;
        const int o  = o_base + ol;
        const float bias = tb[o] + tb2[o];
        #pragma unroll
        for (int nf = 0; nf < 4; ++nf)
          ct[(pl0 + nf * 16) * 136 + ol] =
              f2bf(fmaxf(acc[mf][nf][r2] + bias, 0.f));
      }
    }
    __syncthreads();
    const int p  = tid >> 1;
    const int hf = tid & 1;
    ushort* dst = (ushort*)outp +
                  ((size_t)b * NPIX + h * WW + p) * 256 + o_base + hf * 64;
    const ushort* src = ct + p * 136 + hf * 64;
    #pragma unroll
    for (int j = 0; j < 8; ++j)
      *(us8*)(dst + j * 8) = *(const us8*)(src + j * 8);
    return;
  }

  // EPI 0 / 3: C row = o (coalesced over p within 16-lane groups)
  const int pc0 = h * WW + n0 + (lane & 15);
  #pragma unroll
  for (int mf = 0; mf < 4; ++mf) {
    #pragma unroll
    for (int r2 = 0; r2 < 4; ++r2) {
      const int o = o_base + m0 + mf * 16 + (lane >> 4) * 4 + r2;
      const float bias = tb[o];
      #pragma unroll
      for (int nf = 0; nf < 4; ++nf) {
        const int p = pc0 + nf * 16;
        float v = fmaxf(acc[mf][nf][r2] + bias, 0.f);
        const size_t oi = ((size_t)(b * 256 + o)) * NPIX + p;
        if (EPI == 0) ((ushort*)outp)[oi] = f2bf(v);
        else          ((float*)outp)[oi] = v;
      }
    }
  }
}

// ---------------------------------------------------------------------------
// fused weight repack: fold BN scale, bf16, swizzled LDS-image layout; emit tb.
// W is OIHW flat [COUT_local][CIN][TAPS]; tiles laid out cb + tap*nch + ch.
// ---------------------------------------------------------------------------
struct WSeg {
  const float *W, *g, *bb, *mm, *vv;
  ushort* dst; float* tb;
  int CIN, COUT, TAPS, o_off, cb, start, end;
};

__device__ __forceinline__ void wrepack_one(const WSeg& s, int e) {
  const int tap = e % s.TAPS;
  const int ci  = (e / s.TAPS) % s.CIN;
  const int o   = e / (s.TAPS * s.CIN);
  const int oi  = o + s.o_off;
  const float sc = s.g[o] * rsqrtf(s.vv[o] + EPSV);
  const int nch = s.CIN / 64;
  const int ch = ci >> 6, kl = ci & 63;
  const int slot = (kl >> 3) ^ (oi & 7);
  s.dst[(((size_t)((s.cb + tap * nch + ch) * s.COUT) + oi) << 6) +
        (slot << 3) + (kl & 7)] = f2bf(s.W[e] * sc);
  if (ci == 0 && tap == 0) s.tb[oi] = s.bb[o] - s.mm[o] * sc;
}

__global__ __launch_bounds__(256)
void wrepack_all(WSeg s0, WSeg s1, WSeg s2, WSeg s3, WSeg s4) {
  const int id = blockIdx.x * 256 + threadIdx.x;
  if (id < s0.end)      wrepack_one(s0, id - s0.start);
  else if (id < s1.end) wrepack_one(s1, id - s1.start);
  else if (id < s2.end) wrepack_one(s2, id - s2.start);
  else if (id < s3.end) wrepack_one(s3, id - s3.start);
  else if (id < s4.end) wrepack_one(s4, id - s4.start);
}

// ---------------------------------------------------------------------------
// x (fp32 NCHW) -> xT (bf16 [b][p][256]).  Thread = 4 px x 64 ch.
// ---------------------------------------------------------------------------
__global__ __launch_bounds__(256)
void repack_x(const float* __restrict__ x, ushort* __restrict__ xT)
{
  const int b  = blockIdx.z;
  const int cq = threadIdx.x >> 6;            // channel quarter
  const int pg = threadIdx.x & 63;
  const int p0 = blockIdx.x * 256 + pg * 4;
  const size_t xb = (size_t)b * 256 * NPIX;
  ushort* ob = xT + ((size_t)b * NPIX + p0) * 256 + cq * 64;
  for (int cc = 0; cc < 64; cc += 8) {
    us8 v[4];
    #pragma unroll
    for (int j = 0; j < 8; ++j) {
      const float4 q = *(const float4*)&x[xb + (size_t)(cq * 64 + cc + j) * NPIX + p0];
      v[0][j] = f2bf(q.x); v[1][j] = f2bf(q.y);
      v[2][j] = f2bf(q.z); v[3][j] = f2bf(q.w);
    }
    #pragma unroll
    for (int k = 0; k < 4; ++k)
      *(us8*)(ob + (size_t)k * 256 + cc) = v[k];
  }
}

// ---------------------------------------------------------------------------
// k1: top pool on transposed p12T.  Block (b,w), 128 threads (c in [0,128)).
// Reverse cummax over h of c-half 0; all accesses are contiguous 256B rows.
// topT[b][p][128] out.
// ---------------------------------------------------------------------------
__global__ __launch_bounds__(128)
void scan_top(const ushort* __restrict__ p12T, ushort* __restrict__ topT)
{
  const int b = blockIdx.x >> 7;
  const int w = blockIdx.x & 127;
  const int c = threadIdx.x;
  const size_t ib = (size_t)b * NPIX;
  float cur = -3.4e38f;
  for (int h = HH - 1; h >= 0; --h) {
    const size_t p = ib + h * WW + w;
    cur = fmaxf(cur, bf2f(p12T[p * 256 + c]));
    topT[p * 128 + c] = f2bf(cur);
  }
}

// ---------------------------------------------------------------------------
// k2: left pool + sum.  Block (b,h), 128 threads (c in [0,128)).
// Reverse cummax over w of c-half 1 of p12T, add topT, write sumT[b][p][128].
// ---------------------------------------------------------------------------
__global__ __launch_bounds__(128)
void scan_left_sum(const ushort* __restrict__ p12T,
                   const ushort* __restrict__ topT,
                   ushort* __restrict__ sumT)
{
  const int b = blockIdx.x >> 7;
  const int h = blockIdx.x & 127;
  const int c = threadIdx.x;
  const size_t ib = (size_t)b * NPIX + h * WW;
  float cur = -3.4e38f;
  for (int w = WW - 1; w >= 0; --w) {
    const size_t p = ib + w;
    cur = fmaxf(cur, bf2f(p12T[p * 256 + 128 + c]));
    sumT[p * 128 + c] = f2bf(cur + bf2f(topT[p * 128 + c]));
  }
}

// ---------------------------------------------------------------------------
extern "C" void kernel_launch(void* const* d_in, const int* in_sizes, int n_in,
                              void* d_out, int out_size, void* d_ws, size_t ws_size,
                              hipStream_t stream) {
  const float* x    = (const float*)d_in[0];
  const float* w_p1 = (const float*)d_in[1];
  const float* g_p1 = (const float*)d_in[2];
  const float* b_p1 = (const float*)d_in[3];
  const float* m_p1 = (const float*)d_in[4];
  const float* v_p1 = (const float*)d_in[5];
  const float* w_p2 = (const float*)d_in[6];
  const float* g_p2 = (const float*)d_in[7];
  const float* b_p2 = (const float*)d_in[8];
  const float* m_p2 = (const float*)d_in[9];
  const float* v_p2 = (const float*)d_in[10];
  const float* w_pc = (const float*)d_in[11];
  const float* g_pb = (const float*)d_in[12];
  const float* b_pb = (const float*)d_in[13];
  const float* m_pb = (const float*)d_in[14];
  const float* v_pb = (const float*)d_in[15];
  const float* w_c1 = (const float*)d_in[16];
  const float* g_b1 = (const float*)d_in[17];
  const float* b_b1 = (const float*)d_in[18];
  const float* m_b1 = (const float*)d_in[19];
  const float* v_b1 = (const float*)d_in[20];
  const float* w_c2 = (const float*)d_in[21];
  const float* g_c2 = (const float*)d_in[22];
  const float* b_c2 = (const float*)d_in[23];
  const float* m_c2 = (const float*)d_in[24];
  const float* v_c2 = (const float*)d_in[25];

  char* ws = (char*)d_ws;
  // arena (bytes):
  ushort* xT      = (ushort*)(ws + 0);           // 32MB [b][p][256]
  ushort* p12T    = (ushort*)(ws + 33554432);    // 32MB [b][p][256] transposed
  ushort* relu1T  = (ushort*)(ws + 33554432);    // 32MB alias p12T (dead)
  ushort* sumT    = (ushort*)(ws + 67108864);    // 16MB [b][p][128]
  ushort* topT    = (ushort*)(ws + 83886080);    // 16MB [b][p][128]
  ushort* wR_p12  = (ushort*)(ws + 100663296);   // 36 tiles  (1179648 B)
  ushort* wR_pcc1 = (ushort*)(ws + 101842944);   // 22 tiles  (720896 B)
  ushort* wR_c2   = (ushort*)(ws + 102563840);   // 36 tiles  (1179648 B)
  float*  tb_p12  = (float*)(ws + 103743488);    // 1KB each
  float*  tb_pc   = (float*)(ws + 103744512);
  float*  tb_c1   = (float*)(ws + 103745536);
  float*  tb_c2   = (float*)(ws + 103746560);
  ushort* zerop   = (ushort*)(ws + 103747584);   // 256B zeros
  float*  tb_zero = (float*)(ws + 103747840);    // 1KB zero biases

  hipMemsetAsync(zerop, 0, 256 + 1024, stream);  // zerop + tb_zero

  // fused weight repack (fold BN scale; emit tb)
  const int n_p  = 128 * 256 * 9;    // 294912 (p1 and p2 each)
  const int n_pc = 256 * 128 * 9;    // 294912
  const int n_c1 = 256 * 256 * 1;    // 65536
  const int n_c2 = 256 * 256 * 9;    // 589824
  WSeg s0 = {w_p1, g_p1, b_p1, m_p1, v_p1, wR_p12, tb_p12, 256, 256, 9, 0, 0,
             0, n_p};
  WSeg s1 = {w_p2, g_p2, b_p2, m_p2, v_p2, wR_p12, tb_p12, 256, 256, 9, 128, 0,
             n_p, 2 * n_p};
  WSeg s2 = {w_pc, g_pb, b_pb, m_pb, v_pb, wR_pcc1, tb_pc, 128, 256, 9, 0, 0,
             2 * n_p, 2 * n_p + n_pc};
  WSeg s3 = {w_c1, g_b1, b_b1, m_b1, v_b1, wR_pcc1, tb_c1, 256, 256, 1, 0, 18,
             2 * n_p + n_pc, 2 * n_p + n_pc + n_c1};
  WSeg s4 = {w_c2, g_c2, b_c2, m_c2, v_c2, wR_c2, tb_c2, 256, 256, 9, 0, 0,
             2 * n_p + n_pc + n_c1, 2 * n_p + n_pc + n_c1 + n_c2};
  const int n_all = 2 * n_p + n_pc + n_c1 + n_c2;
  wrepack_all<<<dim3((n_all + 255) / 256), 256, 0, stream>>>(s0, s1, s2, s3, s4);

  // x -> xT
  repack_x<<<dim3(NPIX / 256, 1, BB), 256, 0, stream>>>(x, xT);

  // p12T = relu(bn(conv3x3(x, [w_p1;w_p2]))), TRANSPOSED bf16 [b][p][256]
  convgemm<256, 9, 0, 0, 4><<<dim3(1024), 256, 0, stream>>>(
      xT, nullptr, wR_p12, tb_p12, tb_zero, p12T, zerop);

  // top pool (c 0-127) -> topT; left pool (c 128-255) + sum -> sumT
  scan_top<<<dim3(BB * 128), 128, 0, stream>>>(p12T, topT);
  scan_left_sum<<<dim3(BB * 128), 128, 0, stream>>>(p12T, topT, sumT);

  // relu1T = relu(bn(conv3x3(sumT)) + bn(conv1x1(x))), bf16 [b][p][256]
  // (fused pc + c1; writes transposed directly; overwrites p12T region)
  convgemm<128, 9, 256, 1, 4><<<dim3(1024), 256, 0, stream>>>(
      sumT, xT, wR_pcc1, tb_pc, tb_c1, relu1T, zerop);

  // out = relu(bn(conv3x3(relu1T))), fp32 NCHW
  convgemm<256, 9, 0, 0, 3><<<dim3(1024), 256, 0, stream>>>(
      relu1T, nullptr, wR_c2, tb_c2, nullptr, (void*)d_out, zerop);
}

// Round 13
// 288.591 us; speedup vs baseline: 1.1487x; 1.0364x over previous
//
#include <hip/hip_runtime.h>
#include <hip/hip_bf16.h>

#define HH 128
#define WW 128
#define BB 4
#define NPIX 16384            // HH*WW
#define EPSV 1e-5f

using bfrag = __attribute__((ext_vector_type(8))) short;     // 8 bf16 (4 VGPRs)
using f32x4 = __attribute__((ext_vector_type(4))) float;
using us8   = __attribute__((ext_vector_type(8))) unsigned short;

__device__ __forceinline__ float bf2f(ushort u) {
  union { unsigned int i; float f; } x; x.i = ((unsigned int)u) << 16; return x.f;
}
__device__ __forceinline__ ushort f2bf(float f) {
  union { float f; unsigned int i; } x; x.f = f;
  unsigned int r = x.i + 0x7fffu + ((x.i >> 16) & 1u);   // RNE
  return (ushort)(r >> 16);
}

#define GLOAD16(gsrc, ldst) \
  __builtin_amdgcn_global_load_lds( \
      (const __attribute__((address_space(1))) unsigned int*)(gsrc), \
      (__attribute__((address_space(3))) unsigned int*)(ldst), 16, 0, 0)

// ---------------------------------------------------------------------------
// Implicit-GEMM conv via MFMA (R7 structure verbatim — best measured).
// Double-buffered LDS, ONE barrier per K-tile:
//   vmcnt(0) [tile t loads, issued a full compute ago] -> s_barrier ->
//   stage(t+1, other buf) -> compute(t) [pre-read 16 frags, 32 MFMA].
// WAR-safe: the barrier proves all waves finished compute(t-1), the last
// reader of the buffer stage(t+1) writes.
// Tile: BM=128 outs x BN=128 px (one image row), 4 waves, wave=64x64.
// 64KB LDS -> 2 blocks/CU (cross-block overlap covers barrier bubbles).
// EPI: 0 = relu->bf16 NCHW, 3 = relu->fp32 NCHW,
//      4 = dual-bias, relu, LDS-transposed store -> bf16 [b][p][256].
// Grid: 1024 blocks 1D; XCD g owns h in [16g,16g+16) (L2 halo reuse).
// ---------------------------------------------------------------------------
template<int CIN1, int TAPS1, int CIN2, int TAPS2, int EPI>
__global__ __launch_bounds__(256, 2)
void convgemm(const ushort* __restrict__ B1,    // [b][16384][CIN1] bf16
              const ushort* __restrict__ B2,    // [b][16384][CIN2] bf16 (opt)
              const ushort* __restrict__ wR,    // repacked weights (tiles)
              const float*  __restrict__ tb,    // bias per out-channel
              const float*  __restrict__ tb2,   // second bias (EPI 4)
              void*          __restrict__ outp,
              const ushort* __restrict__ zerop) // 256B of zeros
{
  __shared__ ushort lds[2][16384];              // per buf: 16KB A | 16KB B
  constexpr int nch1 = CIN1 / 64;
  constexpr int nch2 = (CIN2 > 0) ? CIN2 / 64 : 0;
  constexpr int NCH  = TAPS1 * nch1 + TAPS2 * nch2;

  // XCD-locality decode: g = XCD, owns 16 consecutive h for all (b, o-tile)
  const int g  = blockIdx.x & 7;
  const int r  = blockIdx.x >> 3;               // 0..127
  const int bo = r >> 4;                        // b*2 + o
  const int h  = g * 16 + (r & 15);
  const int o_base = (bo & 1) * 128;
  const int b  = bo >> 1;

  const int tid  = threadIdx.x;
  const int lane = tid & 63;
  const int wid  = tid >> 6;
  const int m0 = (wid >> 1) * 64;
  const int n0 = (wid & 1) * 64;

  f32x4 acc[4][4];
  #pragma unroll
  for (int i = 0; i < 4; ++i)
    #pragma unroll
    for (int j = 0; j < 4; ++j) acc[i][j] = (f32x4){0.f, 0.f, 0.f, 0.f};

  // staging lane constants (B side): per segment, LDS pixel-row & k-offset
  int rowB[4], ro1[4], ro2[4];
  #pragma unroll
  for (int s = 0; s < 4; ++s) {
    const int boff = (wid * 4 + s) * 1024 + lane * 16;   // byte off in B image
    rowB[s] = boff >> 7;                                  // pixel row 0..127
    const int sl8 = ((((boff >> 4) & 7) ^ (rowB[s] & 7)) << 3);
    ro1[s] = rowB[s] * CIN1 + sl8;
    ro2[s] = (CIN2 > 0) ? rowB[s] * CIN2 + sl8 : 0;
  }
  const size_t B1base = (size_t)b * NPIX * CIN1;
  const size_t B2base = (CIN2 > 0) ? (size_t)b * NPIX * CIN2 : 0;

  auto stage = [&](int t, int buf) {
    char* base = (char*)&lds[buf][0];
    const ushort* wsrc = wR + ((size_t)t * 256 + o_base) * 64;
    const ushort* bch;
    int zr; bool oob, ph2;
    if (CIN2 == 0 || t < TAPS1 * nch1) {
      const int tap = t / nch1, ch = t - tap * nch1;
      const int dy = (TAPS1 == 9) ? tap / 3 - 1 : 0;
      const int dx = (TAPS1 == 9) ? tap - (tap / 3) * 3 - 1 : 0;
      const int hy = h + dy;
      oob = (hy < 0) | (hy >= HH);
      zr  = (dx < 0) ? 0 : ((dx > 0) ? 127 : -1);
      bch = B1 + B1base + (size_t)(hy * WW + dx) * CIN1 + ch * 64;
      ph2 = false;
    } else {
      const int ch = t - TAPS1 * nch1;
      oob = false; zr = -1;
      bch = B2 + B2base + (size_t)(h * WW) * CIN2 + ch * 64;
      ph2 = true;
    }
    #pragma unroll
    for (int s = 0; s < 4; ++s) {
      const int off = (wid * 4 + s) * 1024;               // bytes
      GLOAD16((const char*)wsrc + off + lane * 16, base + off);
      const int roff = ph2 ? ro2[s] : ro1[s];
      const ushort* bs = (oob || rowB[s] == zr) ? zerop : (bch + roff);
      GLOAD16(bs, base + 16384 + off);
    }
  };

  auto compute = [&](int buf) {
    const char* base = (const char*)&lds[buf][0];
    bfrag af[2][4], bfv[2][4];                  // pre-read both kc frag sets
    #pragma unroll
    for (int kc = 0; kc < 2; ++kc) {
      const int sw = ((((kc << 2) | (lane >> 4)) ^ (lane & 7)) << 4); // bytes
      #pragma unroll
      for (int mf = 0; mf < 4; ++mf)
        af[kc][mf] = *(const bfrag*)(base + (m0 + mf * 16 + (lane & 15)) * 128 + sw);
      #pragma unroll
      for (int nf = 0; nf < 4; ++nf)
        bfv[kc][nf] = *(const bfrag*)(base + 16384 + (n0 + nf * 16 + (lane & 15)) * 128 + sw);
    }
    __builtin_amdgcn_s_setprio(1);
    #pragma unroll
    for (int kc = 0; kc < 2; ++kc)
      #pragma unroll
      for (int mf = 0; mf < 4; ++mf)
        #pragma unroll
        for (int nf = 0; nf < 4; ++nf)
          acc[mf][nf] = __builtin_amdgcn_mfma_f32_16x16x32_bf16(
              af[kc][mf], bfv[kc][nf], acc[mf][nf], 0, 0, 0);
    __builtin_amdgcn_s_setprio(0);
  };

  stage(0, 0);                                   // 8 loads in flight
  int cur = 0;
  for (int t = 0; t < NCH; ++t) {
    asm volatile("s_waitcnt vmcnt(0)" ::: "memory");  // tile t retired (issued
                                                      // a full compute ago)
    __builtin_amdgcn_s_barrier();                // t's LDS valid block-wide;
                                                 // all waves done reading t-1
    __builtin_amdgcn_sched_barrier(0);           // no hoist above barrier
    if (t + 1 < NCH) stage(t + 1, cur ^ 1);      // overlap with compute(t)
    compute(cur);
    cur ^= 1;
  }

  if (EPI == 4) {
    // dual bias + relu, transpose via LDS, store bf16 [b][p][256] rows
    __syncthreads();                             // all compute done, LDS free
    ushort* ct = (ushort*)&lds[0][0];            // [128 px][136] (pad 8)
    const int pl0 = n0 + (lane & 15);
    #pragma unroll
    for (int mf = 0; mf < 4; ++mf) {
      #pragma unroll
      for (int r2 = 0; r2 < 4; ++r2) {
        const int ol = m0 + mf * 16 + (lane >> 4) * 4 + r2;
        const int o  = o_base + ol;
        const float bias = tb[o] + tb2[o];
        #pragma unroll
        for (int nf = 0; nf < 4; ++nf)
          ct[(pl0 + nf * 16) * 136 + ol] =
              f2bf(fmaxf(acc[mf][nf][r2] + bias, 0.f));
      }
    }
    __syncthreads();
    const int p  = tid >> 1;
    const int hf = tid & 1;
    ushort* dst = (ushort*)outp +
                  ((size_t)b * NPIX + h * WW + p) * 256 + o_base + hf * 64;
    const ushort* src = ct + p * 136 + hf * 64;
    #pragma unroll
    for (int j = 0; j < 8; ++j)
      *(us8*)(dst + j * 8) = *(const us8*)(src + j * 8);
    return;
  }

  // EPI 0 / 3: C row = o (coalesced over p within 16-lane groups)
  const int pc0 = h * WW + n0 + (lane & 15);
  #pragma unroll
  for (int mf = 0; mf < 4; ++mf) {
    #pragma unroll
    for (int r2 = 0; r2 < 4; ++r2) {
      const int o = o_base + m0 + mf * 16 + (lane >> 4) * 4 + r2;
      const float bias = tb[o];
      #pragma unroll
      for (int nf = 0; nf < 4; ++nf) {
        const int p = pc0 + nf * 16;
        float v = fmaxf(acc[mf][nf][r2] + bias, 0.f);
        const size_t oi = ((size_t)(b * 256 + o)) * NPIX + p;
        if (EPI == 0) ((ushort*)outp)[oi] = f2bf(v);
        else          ((float*)outp)[oi] = v;
      }
    }
  }
}

// ---------------------------------------------------------------------------
// fused weight repack: fold BN scale, bf16, swizzled LDS-image layout; emit tb.
// W is OIHW flat [COUT_local][CIN][TAPS]; tiles laid out cb + tap*nch + ch.
// ---------------------------------------------------------------------------
struct WSeg {
  const float *W, *g, *bb, *mm, *vv;
  ushort* dst; float* tb;
  int CIN, COUT, TAPS, o_off, cb, start, end;
};

__device__ __forceinline__ void wrepack_one(const WSeg& s, int e) {
  const int tap = e % s.TAPS;
  const int ci  = (e / s.TAPS) % s.CIN;
  const int o   = e / (s.TAPS * s.CIN);
  const int oi  = o + s.o_off;
  const float sc = s.g[o] * rsqrtf(s.vv[o] + EPSV);
  const int nch = s.CIN / 64;
  const int ch = ci >> 6, kl = ci & 63;
  const int slot = (kl >> 3) ^ (oi & 7);
  s.dst[(((size_t)((s.cb + tap * nch + ch) * s.COUT) + oi) << 6) +
        (slot << 3) + (kl & 7)] = f2bf(s.W[e] * sc);
  if (ci == 0 && tap == 0) s.tb[oi] = s.bb[o] - s.mm[o] * sc;
}

__global__ __launch_bounds__(256)
void wrepack_all(WSeg s0, WSeg s1, WSeg s2, WSeg s3, WSeg s4) {
  const int id = blockIdx.x * 256 + threadIdx.x;
  if (id < s0.end)      wrepack_one(s0, id - s0.start);
  else if (id < s1.end) wrepack_one(s1, id - s1.start);
  else if (id < s2.end) wrepack_one(s2, id - s2.start);
  else if (id < s3.end) wrepack_one(s3, id - s3.start);
  else if (id < s4.end) wrepack_one(s4, id - s4.start);
}

// ---------------------------------------------------------------------------
// x (fp32 NCHW) -> xT (bf16 [b][p][256]).  Thread = 4 px x 64 ch.
// ---------------------------------------------------------------------------
__global__ __launch_bounds__(256)
void repack_x(const float* __restrict__ x, ushort* __restrict__ xT)
{
  const int b  = blockIdx.z;
  const int cq = threadIdx.x >> 6;            // channel quarter
  const int pg = threadIdx.x & 63;
  const int p0 = blockIdx.x * 256 + pg * 4;
  const size_t xb = (size_t)b * 256 * NPIX;
  ushort* ob = xT + ((size_t)b * NPIX + p0) * 256 + cq * 64;
  for (int cc = 0; cc < 64; cc += 8) {
    us8 v[4];
    #pragma unroll
    for (int j = 0; j < 8; ++j) {
      const float4 q = *(const float4*)&x[xb + (size_t)(cq * 64 + cc + j) * NPIX + p0];
      v[0][j] = f2bf(q.x); v[1][j] = f2bf(q.y);
      v[2][j] = f2bf(q.z); v[3][j] = f2bf(q.w);
    }
    #pragma unroll
    for (int k = 0; k < 4; ++k)
      *(us8*)(ob + (size_t)k * 256 + cc) = v[k];
  }
}

// ---------------------------------------------------------------------------
// k1: top pool on transposed p12T.  Block (b, w-pair), 256 thr = 2 cols x 128c.
// Reverse cummax over h of c-half 0; unroll-8 prefetch hides load latency
// (8 independent loads per chunk, then the serial fmax chain runs on regs).
// topT[b][p][128] out.
// ---------------------------------------------------------------------------
__global__ __launch_bounds__(256)
void scan_top(const ushort* __restrict__ p12T, ushort* __restrict__ topT)
{
  const int b = blockIdx.x >> 6;
  const int w = (blockIdx.x & 63) * 2 + (threadIdx.x >> 7);
  const int c = threadIdx.x & 127;
  const size_t ib = (size_t)b * NPIX;
  float cur = -3.4e38f;
  for (int h8 = HH - 8; h8 >= 0; h8 -= 8) {
    float v[8];
    #pragma unroll
    for (int j = 0; j < 8; ++j)
      v[j] = bf2f(p12T[(ib + (size_t)(h8 + j) * WW + w) * 256 + c]);
    #pragma unroll
    for (int j = 7; j >= 0; --j) {
      cur = fmaxf(cur, v[j]);
      topT[(ib + (size_t)(h8 + j) * WW + w) * 128 + c] = f2bf(cur);
    }
  }
}

// ---------------------------------------------------------------------------
// k2: left pool + sum.  Block (b, h-pair), 256 thr = 2 rows x 128c.
// Reverse cummax over w of c-half 1 of p12T, add topT, write sumT[b][p][128].
// Unroll-8 prefetch (16 independent loads per chunk).
// ---------------------------------------------------------------------------
__global__ __launch_bounds__(256)
void scan_left_sum(const ushort* __restrict__ p12T,
                   const ushort* __restrict__ topT,
                   ushort* __restrict__ sumT)
{
  const int b = blockIdx.x >> 6;
  const int h = (blockIdx.x & 63) * 2 + (threadIdx.x >> 7);
  const int c = threadIdx.x & 127;
  const size_t ib = (size_t)b * NPIX + (size_t)h * WW;
  float cur = -3.4e38f;
  for (int w8 = WW - 8; w8 >= 0; w8 -= 8) {
    float v[8], tv[8];
    #pragma unroll
    for (int j = 0; j < 8; ++j) {
      v[j]  = bf2f(p12T[(ib + w8 + j) * 256 + 128 + c]);
      tv[j] = bf2f(topT[(ib + w8 + j) * 128 + c]);
    }
    #pragma unroll
    for (int j = 7; j >= 0; --j) {
      cur = fmaxf(cur, v[j]);
      sumT[(ib + w8 + j) * 128 + c] = f2bf(cur + tv[j]);
    }
  }
}

// ---------------------------------------------------------------------------
extern "C" void kernel_launch(void* const* d_in, const int* in_sizes, int n_in,
                              void* d_out, int out_size, void* d_ws, size_t ws_size,
                              hipStream_t stream) {
  const float* x    = (const float*)d_in[0];
  const float* w_p1 = (const float*)d_in[1];
  const float* g_p1 = (const float*)d_in[2];
  const float* b_p1 = (const float*)d_in[3];
  const float* m_p1 = (const float*)d_in[4];
  const float* v_p1 = (const float*)d_in[5];
  const float* w_p2 = (const float*)d_in[6];
  const float* g_p2 = (const float*)d_in[7];
  const float* b_p2 = (const float*)d_in[8];
  const float* m_p2 = (const float*)d_in[9];
  const float* v_p2 = (const float*)d_in[10];
  const float* w_pc = (const float*)d_in[11];
  const float* g_pb = (const float*)d_in[12];
  const float* b_pb = (const float*)d_in[13];
  const float* m_pb = (const float*)d_in[14];
  const float* v_pb = (const float*)d_in[15];
  const float* w_c1 = (const float*)d_in[16];
  const float* g_b1 = (const float*)d_in[17];
  const float* b_b1 = (const float*)d_in[18];
  const float* m_b1 = (const float*)d_in[19];
  const float* v_b1 = (const float*)d_in[20];
  const float* w_c2 = (const float*)d_in[21];
  const float* g_c2 = (const float*)d_in[22];
  const float* b_c2 = (const float*)d_in[23];
  const float* m_c2 = (const float*)d_in[24];
  const float* v_c2 = (const float*)d_in[25];

  char* ws = (char*)d_ws;
  // arena (bytes):
  ushort* xT      = (ushort*)(ws + 0);           // 32MB [b][p][256]
  ushort* p12T    = (ushort*)(ws + 33554432);    // 32MB [b][p][256] transposed
  ushort* relu1T  = (ushort*)(ws + 33554432);    // 32MB alias p12T (dead)
  ushort* sumT    = (ushort*)(ws + 67108864);    // 16MB [b][p][128]
  ushort* topT    = (ushort*)(ws + 83886080);    // 16MB [b][p][128]
  ushort* wR_p12  = (ushort*)(ws + 100663296);   // 36 tiles  (1179648 B)
  ushort* wR_pcc1 = (ushort*)(ws + 101842944);   // 22 tiles  (720896 B)
  ushort* wR_c2   = (ushort*)(ws + 102563840);   // 36 tiles  (1179648 B)
  float*  tb_p12  = (float*)(ws + 103743488);    // 1KB each
  float*  tb_pc   = (float*)(ws + 103744512);
  float*  tb_c1   = (float*)(ws + 103745536);
  float*  tb_c2   = (float*)(ws + 103746560);
  ushort* zerop   = (ushort*)(ws + 103747584);   // 256B zeros
  float*  tb_zero = (float*)(ws + 103747840);    // 1KB zero biases

  hipMemsetAsync(zerop, 0, 256 + 1024, stream);  // zerop + tb_zero

  // fused weight repack (fold BN scale; emit tb)
  const int n_p  = 128 * 256 * 9;    // 294912 (p1 and p2 each)
  const int n_pc = 256 * 128 * 9;    // 294912
  const int n_c1 = 256 * 256 * 1;    // 65536
  const int n_c2 = 256 * 256 * 9;    // 589824
  WSeg s0 = {w_p1, g_p1, b_p1, m_p1, v_p1, wR_p12, tb_p12, 256, 256, 9, 0, 0,
             0, n_p};
  WSeg s1 = {w_p2, g_p2, b_p2, m_p2, v_p2, wR_p12, tb_p12, 256, 256, 9, 128, 0,
             n_p, 2 * n_p};
  WSeg s2 = {w_pc, g_pb, b_pb, m_pb, v_pb, wR_pcc1, tb_pc, 128, 256, 9, 0, 0,
             2 * n_p, 2 * n_p + n_pc};
  WSeg s3 = {w_c1, g_b1, b_b1, m_b1, v_b1, wR_pcc1, tb_c1, 256, 256, 1, 0, 18,
             2 * n_p + n_pc, 2 * n_p + n_pc + n_c1};
  WSeg s4 = {w_c2, g_c2, b_c2, m_c2, v_c2, wR_c2, tb_c2, 256, 256, 9, 0, 0,
             2 * n_p + n_pc + n_c1, 2 * n_p + n_pc + n_c1 + n_c2};
  const int n_all = 2 * n_p + n_pc + n_c1 + n_c2;
  wrepack_all<<<dim3((n_all + 255) / 256), 256, 0, stream>>>(s0, s1, s2, s3, s4);

  // x -> xT
  repack_x<<<dim3(NPIX / 256, 1, BB), 256, 0, stream>>>(x, xT);

  // p12T = relu(bn(conv3x3(x, [w_p1;w_p2]))), TRANSPOSED bf16 [b][p][256]
  convgemm<256, 9, 0, 0, 4><<<dim3(1024), 256, 0, stream>>>(
      xT, nullptr, wR_p12, tb_p12, tb_zero, p12T, zerop);

  // top pool (c 0-127) -> topT; left pool (c 128-255) + sum -> sumT
  scan_top<<<dim3(BB * 64), 256, 0, stream>>>(p12T, topT);
  scan_left_sum<<<dim3(BB * 64), 256, 0, stream>>>(p12T, topT, sumT);

  // relu1T = relu(bn(conv3x3(sumT)) + bn(conv1x1(x))), bf16 [b][p][256]
  // (fused pc + c1; writes transposed directly; overwrites p12T region)
  convgemm<128, 9, 256, 1, 4><<<dim3(1024), 256, 0, stream>>>(
      sumT, xT, wR_pcc1, tb_pc, tb_c1, relu1T, zerop);

  // out = relu(bn(conv3x3(relu1T))), fp32 NCHW
  convgemm<256, 9, 0, 0, 3><<<dim3(1024), 256, 0, stream>>>(
      relu1T, nullptr, wR_c2, tb_c2, nullptr, (void*)d_out, zerop);
}

// Round 14
// 281.539 us; speedup vs baseline: 1.1774x; 1.0250x over previous
//
#include <hip/hip_runtime.h>
#include <hip/hip_bf16.h>

#define HH 128
#define WW 128
#define BB 4
#define NPIX 16384            // HH*WW
#define EPSV 1e-5f

using bfrag = __attribute__((ext_vector_type(8))) short;     // 8 bf16 (4 VGPRs)
using f32x4 = __attribute__((ext_vector_type(4))) float;
using us8   = __attribute__((ext_vector_type(8))) unsigned short;

__device__ __forceinline__ float bf2f(ushort u) {
  union { unsigned int i; float f; } x; x.i = ((unsigned int)u) << 16; return x.f;
}
__device__ __forceinline__ ushort f2bf(float f) {
  union { float f; unsigned int i; } x; x.f = f;
  unsigned int r = x.i + 0x7fffu + ((x.i >> 16) & 1u);   // RNE
  return (ushort)(r >> 16);
}

#define GLOAD16(gsrc, ldst) \
  __builtin_amdgcn_global_load_lds( \
      (const __attribute__((address_space(1))) unsigned int*)(gsrc), \
      (__attribute__((address_space(3))) unsigned int*)(ldst), 16, 0, 0)

// ---------------------------------------------------------------------------
// Implicit-GEMM conv via MFMA — 256x256 tile with R7's sync discipline.
// Tile: BM=256 outs x BN=256 px (rows 2h,2h+1) x BK=64; 8 waves (2M x 4N),
// per-wave 128x64 (acc[8][4]).  LDS: 2 x (A 32KB | B 32KB) = 128KB, 1 blk/CU.
// Per K-tile: ONE vmcnt(0) [loads issued a full compute phase ago] + ONE
// barrier, then stage(t+1) all 8 loads, then 4 interleaved phases of
// {ds_read cluster -> 16 MFMA} (B frags register-cached across M-halves).
// No mid-tile barriers: waves slip freely; 2 waves/SIMD overlap MFMA w/ LDS.
// Rationale: 256^2 halves per-FLOP LDS reads vs 128^2 (bound 60->30us for
// c2); R8/R10 lost the benefit to 2 vmcnt-gated barriers per tile.
// EPI: 0 = relu->bf16 NCHW, 3 = relu->fp32 NCHW,
//      4 = dual-bias, relu, LDS-transposed store -> bf16 [b][p][256].
// ---------------------------------------------------------------------------
template<int CIN1, int TAPS1, int CIN2, int TAPS2, int EPI>
__global__ __launch_bounds__(512, 1)
void convgemm(const ushort* __restrict__ B1,    // [b][16384][CIN1] bf16
              const ushort* __restrict__ B2,    // [b][16384][CIN2] bf16 (opt)
              const ushort* __restrict__ wR,    // repacked weights (tiles)
              const float*  __restrict__ tb,    // bias per out-channel
              const float*  __restrict__ tb2,   // second bias (EPI 4)
              void*          __restrict__ outp,
              const ushort* __restrict__ zerop) // 256B of zeros
{
  __shared__ char ldsb[131072];                 // 2 x (A 32KB | B 32KB)
  constexpr int nch1 = CIN1 / 64;
  constexpr int nch2 = (CIN2 > 0) ? CIN2 / 64 : 0;
  constexpr int NCH  = TAPS1 * nch1 + TAPS2 * nch2;

  // grid 256: XCD g = bid&7 owns 32 contiguous nids (h-locality per L2)
  const int nid = (blockIdx.x & 7) * 32 + (blockIdx.x >> 3);
  const int b   = nid >> 6;
  const int h2  = (nid & 63) * 2;               // first of the two rows

  const int tid  = threadIdx.x;
  const int lane = tid & 63;
  const int wid  = tid >> 6;
  const int wc   = wid & 3;                     // N-wave (0..3)
  const int m0   = (wid >> 2) * 128;            // M-wave (0..1) -> 128 rows
  const int n0   = wc * 64;

  f32x4 acc[8][4];
  #pragma unroll
  for (int i = 0; i < 8; ++i)
    #pragma unroll
    for (int j = 0; j < 4; ++j) acc[i][j] = (f32x4){0.f, 0.f, 0.f, 0.f};

  // B staging constants: seg s covers pixel rows s*64..s*64+63 (8KB each)
  const int sl8 = (((tid & 7) ^ ((tid >> 3) & 7)) << 3);   // inv-swizzle k-off
  int ro1[4], ro2[4], w_[4], prow_[4];
  #pragma unroll
  for (int s = 0; s < 4; ++s) {
    const int rowB = s * 64 + (tid >> 3);       // pixel index 0..255
    prow_[s] = rowB >> 7;                       // 0: row 2h, 1: row 2h+1
    w_[s]    = rowB & 127;
    ro1[s]   = (prow_[s] * WW + w_[s]) * CIN1 + sl8;
    ro2[s]   = (CIN2 > 0) ? rowB * CIN2 + sl8 : 0;
  }
  const size_t B1base = (size_t)b * NPIX * CIN1;
  const size_t B2base = (CIN2 > 0) ? (size_t)b * NPIX * CIN2 : 0;

  auto stage = [&](int t, int buf) {            // 8 loads: B0..B3, A0..A3
    char* baseA = ldsb + buf * 65536;
    char* baseB = baseA + 32768;
    if (CIN2 == 0 || t < TAPS1 * nch1) {
      const int tap = t / nch1, ch = t - tap * nch1;
      const int dy = (TAPS1 == 9) ? tap / 3 - 1 : 0;
      const int dx = (TAPS1 == 9) ? tap - (tap / 3) * 3 - 1 : 0;
      const int hy0 = h2 + dy;
      const bool oob0 = (hy0 < 0) | (hy0 > 127);
      const bool oob1 = (hy0 + 1 < 0) | (hy0 + 1 > 127);
      const int zr = (dx < 0) ? 0 : ((dx > 0) ? 127 : -1);
      const ushort* bch = B1 + B1base + (size_t)(hy0 * WW + dx) * CIN1 + ch * 64;
      #pragma unroll
      for (int s = 0; s < 4; ++s) {
        const bool bad = (prow_[s] ? oob1 : oob0) || (w_[s] == zr);
        const ushort* src = bad ? zerop : (bch + ro1[s]);
        GLOAD16(src, baseB + s * 8192 + tid * 16);
      }
    } else {
      const int ch = t - TAPS1 * nch1;
      const ushort* bch = B2 + B2base + (size_t)(h2 * WW) * CIN2 + ch * 64;
      #pragma unroll
      for (int s = 0; s < 4; ++s)
        GLOAD16(bch + ro2[s], baseB + s * 8192 + tid * 16);
    }
    const char* wsrc = (const char*)(wR + (size_t)t * (256 * 64));
    #pragma unroll
    for (int i = 0; i < 4; ++i)                 // A: 4 loads (32KB, linear)
      GLOAD16(wsrc + i * 8192 + tid * 16, baseA + i * 8192 + tid * 16);
  };

#define READ_A(dst_, mfh_, kc_) do { \
    const int sw_ = ((((kc_) << 2) | (lane >> 4)) ^ (lane & 7)) << 4; \
    _Pragma("unroll") \
    for (int mf_ = 0; mf_ < 4; ++mf_) \
      dst_[mf_] = *(const bfrag*)(cb + \
          (m0 + (mfh_) * 64 + mf_ * 16 + (lane & 15)) * 128 + sw_); \
  } while (0)

#define READ_B(dst_, kc_) do { \
    const int sw_ = ((((kc_) << 2) | (lane >> 4)) ^ (lane & 7)) << 4; \
    _Pragma("unroll") \
    for (int nf_ = 0; nf_ < 4; ++nf_) \
      dst_[nf_] = *(const bfrag*)(cb + 32768 + \
          (n0 + nf_ * 16 + (lane & 15)) * 128 + sw_); \
  } while (0)

#define MFMA16(rb_, A_, B_) do { \
    __builtin_amdgcn_s_setprio(1); \
    _Pragma("unroll") \
    for (int mf_ = 0; mf_ < 4; ++mf_) \
      _Pragma("unroll") \
      for (int nf_ = 0; nf_ < 4; ++nf_) \
        acc[(rb_) + mf_][nf_] = __builtin_amdgcn_mfma_f32_16x16x32_bf16( \
            A_[mf_], B_[nf_], acc[(rb_) + mf_][nf_], 0, 0, 0); \
    __builtin_amdgcn_s_setprio(0); \
  } while (0)

  stage(0, 0);                                   // 8 loads in flight
  for (int t = 0; t < NCH; ++t) {
    asm volatile("s_waitcnt vmcnt(0)" ::: "memory"); // tile t retired (issued
                                                     // a full compute ago)
    __builtin_amdgcn_s_barrier();                // t's LDS valid block-wide;
                                                 // all waves done reading t-1
    __builtin_amdgcn_sched_barrier(0);           // no hoist above barrier
    if (t + 1 < NCH) stage(t + 1, (t + 1) & 1);  // issue all 8 loads early
    __builtin_amdgcn_sched_barrier(0);           // keep them before compute
    const char* cb = ldsb + (t & 1) * 65536;
    bfrag B0[4], B1f[4], A00[4], A10[4], A01[4], A11[4];
    READ_B(B0, 0);
    READ_A(A00, 0, 0);
    MFMA16(0, A00, B0);                          // rows 0-3, kc0
    READ_A(A10, 1, 0);
    MFMA16(4, A10, B0);                          // rows 4-7, kc0
    READ_B(B1f, 1);
    READ_A(A01, 0, 1);
    MFMA16(0, A01, B1f);                         // rows 0-3, kc1
    READ_A(A11, 1, 1);
    MFMA16(4, A11, B1f);                         // rows 4-7, kc1
  }
#undef READ_A
#undef READ_B
#undef MFMA16

  if (EPI == 4) {
    // dual bias + relu; transpose via LDS in two 128-pixel passes
    ushort* ct = (ushort*)ldsb;                  // [128 px][264] per pass
    #pragma unroll
    for (int ph = 0; ph < 2; ++ph) {
      __syncthreads();
      if ((wc >> 1) == ph) {
        const int lp0 = (wc & 1) * 64 + (lane & 15);
        #pragma unroll
        for (int mf = 0; mf < 8; ++mf) {
          #pragma unroll
          for (int r2 = 0; r2 < 4; ++r2) {
            const int o = m0 + mf * 16 + (lane >> 4) * 4 + r2;
            const float bias = tb[o] + tb2[o];
            #pragma unroll
            for (int nf = 0; nf < 4; ++nf)
              ct[(lp0 + nf * 16) * 264 + o] =
                  f2bf(fmaxf(acc[mf][nf][r2] + bias, 0.f));
          }
        }
      }
      __syncthreads();
      const int lp = tid >> 2;
      const int q  = tid & 3;
      ushort* dst = (ushort*)outp +
          ((size_t)b * NPIX + (h2 + ph) * WW + lp) * 256 + q * 64;
      const ushort* src = ct + lp * 264 + q * 64;
      #pragma unroll
      for (int j = 0; j < 8; ++j)
        *(us8*)(dst + j * 8) = *(const us8*)(src + j * 8);
    }
    return;
  }

  // EPI 0 / 3: C[o][p]; p spans two rows (prow fixed per wave)
  const int prow = wc >> 1;
  const int hout = h2 + prow;
  const int wbase = (wc & 1) * 64 + (lane & 15);
  #pragma unroll
  for (int mf = 0; mf < 8; ++mf) {
    #pragma unroll
    for (int r2 = 0; r2 < 4; ++r2) {
      const int o = m0 + mf * 16 + (lane >> 4) * 4 + r2;
      const float bias = tb[o];
      #pragma unroll
      for (int nf = 0; nf < 4; ++nf) {
        const int w = wbase + nf * 16;
        float v = fmaxf(acc[mf][nf][r2] + bias, 0.f);
        const size_t oi = (((size_t)(b * 256 + o)) << 14) + hout * WW + w;
        if (EPI == 0) ((ushort*)outp)[oi] = f2bf(v);
        else          ((float*)outp)[oi] = v;
      }
    }
  }
}

// ---------------------------------------------------------------------------
// fused weight repack: fold BN scale, bf16, swizzled LDS-image layout; emit tb.
// W is OIHW flat [COUT_local][CIN][TAPS]; tiles laid out cb + tap*nch + ch.
// ---------------------------------------------------------------------------
struct WSeg {
  const float *W, *g, *bb, *mm, *vv;
  ushort* dst; float* tb;
  int CIN, COUT, TAPS, o_off, cb, start, end;
};

__device__ __forceinline__ void wrepack_one(const WSeg& s, int e) {
  const int tap = e % s.TAPS;
  const int ci  = (e / s.TAPS) % s.CIN;
  const int o   = e / (s.TAPS * s.CIN);
  const int oi  = o + s.o_off;
  const float sc = s.g[o] * rsqrtf(s.vv[o] + EPSV);
  const int nch = s.CIN / 64;
  const int ch = ci >> 6, kl = ci & 63;
  const int slot = (kl >> 3) ^ (oi & 7);
  s.dst[(((size_t)((s.cb + tap * nch + ch) * s.COUT) + oi) << 6) +
        (slot << 3) + (kl & 7)] = f2bf(s.W[e] * sc);
  if (ci == 0 && tap == 0) s.tb[oi] = s.bb[o] - s.mm[o] * sc;
}

__global__ __launch_bounds__(256)
void wrepack_all(WSeg s0, WSeg s1, WSeg s2, WSeg s3, WSeg s4) {
  const int id = blockIdx.x * 256 + threadIdx.x;
  if (id < s0.end)      wrepack_one(s0, id - s0.start);
  else if (id < s1.end) wrepack_one(s1, id - s1.start);
  else if (id < s2.end) wrepack_one(s2, id - s2.start);
  else if (id < s3.end) wrepack_one(s3, id - s3.start);
  else if (id < s4.end) wrepack_one(s4, id - s4.start);
}

// ---------------------------------------------------------------------------
// x (fp32 NCHW) -> xT (bf16 [b][p][256]).  Thread = 4 px x 64 ch.
// ---------------------------------------------------------------------------
__global__ __launch_bounds__(256)
void repack_x(const float* __restrict__ x, ushort* __restrict__ xT)
{
  const int b  = blockIdx.z;
  const int cq = threadIdx.x >> 6;            // channel quarter
  const int pg = threadIdx.x & 63;
  const int p0 = blockIdx.x * 256 + pg * 4;
  const size_t xb = (size_t)b * 256 * NPIX;
  ushort* ob = xT + ((size_t)b * NPIX + p0) * 256 + cq * 64;
  for (int cc = 0; cc < 64; cc += 8) {
    us8 v[4];
    #pragma unroll
    for (int j = 0; j < 8; ++j) {
      const float4 q = *(const float4*)&x[xb + (size_t)(cq * 64 + cc + j) * NPIX + p0];
      v[0][j] = f2bf(q.x); v[1][j] = f2bf(q.y);
      v[2][j] = f2bf(q.z); v[3][j] = f2bf(q.w);
    }
    #pragma unroll
    for (int k = 0; k < 4; ++k)
      *(us8*)(ob + (size_t)k * 256 + cc) = v[k];
  }
}

// ---------------------------------------------------------------------------
// k1: top pool on transposed p12T.  Block (b, w-pair), 256 thr = 2 cols x 128c.
// Reverse cummax over h of c-half 0; unroll-8 prefetch hides load latency.
// topT[b][p][128] out.
// ---------------------------------------------------------------------------
__global__ __launch_bounds__(256)
void scan_top(const ushort* __restrict__ p12T, ushort* __restrict__ topT)
{
  const int b = blockIdx.x >> 6;
  const int w = (blockIdx.x & 63) * 2 + (threadIdx.x >> 7);
  const int c = threadIdx.x & 127;
  const size_t ib = (size_t)b * NPIX;
  float cur = -3.4e38f;
  for (int h8 = HH - 8; h8 >= 0; h8 -= 8) {
    float v[8];
    #pragma unroll
    for (int j = 0; j < 8; ++j)
      v[j] = bf2f(p12T[(ib + (size_t)(h8 + j) * WW + w) * 256 + c]);
    #pragma unroll
    for (int j = 7; j >= 0; --j) {
      cur = fmaxf(cur, v[j]);
      topT[(ib + (size_t)(h8 + j) * WW + w) * 128 + c] = f2bf(cur);
    }
  }
}

// ---------------------------------------------------------------------------
// k2: left pool + sum.  Block (b, h-pair), 256 thr = 2 rows x 128c.
// Reverse cummax over w of c-half 1 of p12T, add topT, write sumT[b][p][128].
// ---------------------------------------------------------------------------
__global__ __launch_bounds__(256)
void scan_left_sum(const ushort* __restrict__ p12T,
                   const ushort* __restrict__ topT,
                   ushort* __restrict__ sumT)
{
  const int b = blockIdx.x >> 6;
  const int h = (blockIdx.x & 63) * 2 + (threadIdx.x >> 7);
  const int c = threadIdx.x & 127;
  const size_t ib = (size_t)b * NPIX + (size_t)h * WW;
  float cur = -3.4e38f;
  for (int w8 = WW - 8; w8 >= 0; w8 -= 8) {
    float v[8], tv[8];
    #pragma unroll
    for (int j = 0; j < 8; ++j) {
      v[j]  = bf2f(p12T[(ib + w8 + j) * 256 + 128 + c]);
      tv[j] = bf2f(topT[(ib + w8 + j) * 128 + c]);
    }
    #pragma unroll
    for (int j = 7; j >= 0; --j) {
      cur = fmaxf(cur, v[j]);
      sumT[(ib + w8 + j) * 128 + c] = f2bf(cur + tv[j]);
    }
  }
}

// ---------------------------------------------------------------------------
extern "C" void kernel_launch(void* const* d_in, const int* in_sizes, int n_in,
                              void* d_out, int out_size, void* d_ws, size_t ws_size,
                              hipStream_t stream) {
  const float* x    = (const float*)d_in[0];
  const float* w_p1 = (const float*)d_in[1];
  const float* g_p1 = (const float*)d_in[2];
  const float* b_p1 = (const float*)d_in[3];
  const float* m_p1 = (const float*)d_in[4];
  const float* v_p1 = (const float*)d_in[5];
  const float* w_p2 = (const float*)d_in[6];
  const float* g_p2 = (const float*)d_in[7];
  const float* b_p2 = (const float*)d_in[8];
  const float* m_p2 = (const float*)d_in[9];
  const float* v_p2 = (const float*)d_in[10];
  const float* w_pc = (const float*)d_in[11];
  const float* g_pb = (const float*)d_in[12];
  const float* b_pb = (const float*)d_in[13];
  const float* m_pb = (const float*)d_in[14];
  const float* v_pb = (const float*)d_in[15];
  const float* w_c1 = (const float*)d_in[16];
  const float* g_b1 = (const float*)d_in[17];
  const float* b_b1 = (const float*)d_in[18];
  const float* m_b1 = (const float*)d_in[19];
  const float* v_b1 = (const float*)d_in[20];
  const float* w_c2 = (const float*)d_in[21];
  const float* g_c2 = (const float*)d_in[22];
  const float* b_c2 = (const float*)d_in[23];
  const float* m_c2 = (const float*)d_in[24];
  const float* v_c2 = (const float*)d_in[25];

  char* ws = (char*)d_ws;
  // arena (bytes):
  ushort* xT      = (ushort*)(ws + 0);           // 32MB [b][p][256]
  ushort* p12T    = (ushort*)(ws + 33554432);    // 32MB [b][p][256] transposed
  ushort* relu1T  = (ushort*)(ws + 33554432);    // 32MB alias p12T (dead)
  ushort* sumT    = (ushort*)(ws + 67108864);    // 16MB [b][p][128]
  ushort* topT    = (ushort*)(ws + 83886080);    // 16MB [b][p][128]
  ushort* wR_p12  = (ushort*)(ws + 100663296);   // 36 tiles  (1179648 B)
  ushort* wR_pcc1 = (ushort*)(ws + 101842944);   // 22 tiles  (720896 B)
  ushort* wR_c2   = (ushort*)(ws + 102563840);   // 36 tiles  (1179648 B)
  float*  tb_p12  = (float*)(ws + 103743488);    // 1KB each
  float*  tb_pc   = (float*)(ws + 103744512);
  float*  tb_c1   = (float*)(ws + 103745536);
  float*  tb_c2   = (float*)(ws + 103746560);
  ushort* zerop   = (ushort*)(ws + 103747584);   // 256B zeros
  float*  tb_zero = (float*)(ws + 103747840);    // 1KB zero biases

  hipMemsetAsync(zerop, 0, 256 + 1024, stream);  // zerop + tb_zero

  // fused weight repack (fold BN scale; emit tb)
  const int n_p  = 128 * 256 * 9;    // 294912 (p1 and p2 each)
  const int n_pc = 256 * 128 * 9;    // 294912
  const int n_c1 = 256 * 256 * 1;    // 65536
  const int n_c2 = 256 * 256 * 9;    // 589824
  WSeg s0 = {w_p1, g_p1, b_p1, m_p1, v_p1, wR_p12, tb_p12, 256, 256, 9, 0, 0,
             0, n_p};
  WSeg s1 = {w_p2, g_p2, b_p2, m_p2, v_p2, wR_p12, tb_p12, 256, 256, 9, 128, 0,
             n_p, 2 * n_p};
  WSeg s2 = {w_pc, g_pb, b_pb, m_pb, v_pb, wR_pcc1, tb_pc, 128, 256, 9, 0, 0,
             2 * n_p, 2 * n_p + n_pc};
  WSeg s3 = {w_c1, g_b1, b_b1, m_b1, v_b1, wR_pcc1, tb_c1, 256, 256, 1, 0, 18,
             2 * n_p + n_pc, 2 * n_p + n_pc + n_c1};
  WSeg s4 = {w_c2, g_c2, b_c2, m_c2, v_c2, wR_c2, tb_c2, 256, 256, 9, 0, 0,
             2 * n_p + n_pc + n_c1, 2 * n_p + n_pc + n_c1 + n_c2};
  const int n_all = 2 * n_p + n_pc + n_c1 + n_c2;
  wrepack_all<<<dim3((n_all + 255) / 256), 256, 0, stream>>>(s0, s1, s2, s3, s4);

  // x -> xT
  repack_x<<<dim3(NPIX / 256, 1, BB), 256, 0, stream>>>(x, xT);

  // p12T = relu(bn(conv3x3(x, [w_p1;w_p2]))), TRANSPOSED bf16 [b][p][256]
  convgemm<256, 9, 0, 0, 4><<<dim3(256), 512, 0, stream>>>(
      xT, nullptr, wR_p12, tb_p12, tb_zero, p12T, zerop);

  // top pool (c 0-127) -> topT; left pool (c 128-255) + sum -> sumT
  scan_top<<<dim3(BB * 64), 256, 0, stream>>>(p12T, topT);
  scan_left_sum<<<dim3(BB * 64), 256, 0, stream>>>(p12T, topT, sumT);

  // relu1T = relu(bn(conv3x3(sumT)) + bn(conv1x1(x))), bf16 [b][p][256]
  // (fused pc + c1; writes transposed directly; overwrites p12T region)
  convgemm<128, 9, 256, 1, 4><<<dim3(256), 512, 0, stream>>>(
      sumT, xT, wR_pcc1, tb_pc, tb_c1, relu1T, zerop);

  // out = relu(bn(conv3x3(relu1T))), fp32 NCHW
  convgemm<256, 9, 0, 0, 3><<<dim3(256), 512, 0, stream>>>(
      relu1T, nullptr, wR_c2, tb_c2, nullptr, (void*)d_out, zerop);
}

// Round 15
// 268.097 us; speedup vs baseline: 1.2365x; 1.0501x over previous
//
#include <hip/hip_runtime.h>
#include <hip/hip_bf16.h>

#define HH 128
#define WW 128
#define BB 4
#define NPIX 16384            // HH*WW
#define EPSV 1e-5f

using bfrag = __attribute__((ext_vector_type(8))) short;     // 8 bf16 (4 VGPRs)
using f32x4 = __attribute__((ext_vector_type(4))) float;
using us8   = __attribute__((ext_vector_type(8))) unsigned short;

__device__ __forceinline__ float bf2f(ushort u) {
  union { unsigned int i; float f; } x; x.i = ((unsigned int)u) << 16; return x.f;
}
__device__ __forceinline__ ushort f2bf(float f) {
  union { float f; unsigned int i; } x; x.f = f;
  unsigned int r = x.i + 0x7fffu + ((x.i >> 16) & 1u);   // RNE
  return (ushort)(r >> 16);
}

#define GLOAD16(gsrc, ldst) \
  __builtin_amdgcn_global_load_lds( \
      (const __attribute__((address_space(1))) unsigned int*)(gsrc), \
      (__attribute__((address_space(3))) unsigned int*)(ldst), 16, 0, 0)

// ---------------------------------------------------------------------------
// Implicit-GEMM conv via MFMA (proven 128^2 R7 structure) + DX-SHARING:
// a 3x3 conv stages the same B row for dx=-1/0/+1; here the K-loop runs over
// (dy,ch) GROUPS, staging B ONCE per group into a 130-row LDS image
// (row 0 & 129 = permanent zero halo, rows 1..128 = pixels), and dx becomes
// a row shift in the ds_read (edges read the halo).  B staging VMEM + LDS
// writes drop 3x for 3x3 taps; A-tiles double-buffered per tap as before.
// Sync per tap unchanged: vmcnt(0) [loads issued a full compute-phase ago]
// + ONE barrier; B prefetched one tap ahead at group boundaries (WAR slack
// = 3 barriers).
// Tile: BM=128 outs x BN=128 px (one image row), 4 waves, wave=64x64.
// LDS 66KB -> 2 blocks/CU.  Grid 1024; XCD g owns h in [16g,16g+16).
// EPI: 0 = relu->bf16 NCHW, 3 = relu->fp32 NCHW,
//      4 = dual-bias, relu, LDS-transposed store -> bf16 [b][p][256].
// ---------------------------------------------------------------------------
template<int CIN1, int TAPS1, int CIN2, int TAPS2, int EPI>
__global__ __launch_bounds__(256, 2)
void convgemm(const ushort* __restrict__ B1,    // [b][16384][CIN1] bf16
              const ushort* __restrict__ B2,    // [b][16384][CIN2] bf16 (opt)
              const ushort* __restrict__ wR,    // repacked weights (tiles)
              const float*  __restrict__ tb,    // bias per out-channel
              const float*  __restrict__ tb2,   // second bias (EPI 4)
              void*          __restrict__ outp,
              const ushort* __restrict__ zerop) // 256B of zeros
{
  // layout: A0 @0 (16KB), A1 @16384, B0 @32768 (16640B), B1 @49408
  __shared__ char ldsbuf[66048];
  constexpr int nch1 = CIN1 / 64;
  constexpr int nch2 = (CIN2 > 0) ? CIN2 / 64 : 0;
  constexpr int NG1  = 3 * nch1;                // (dy,ch) groups
  constexpr int NT1  = 9 * nch1;                // 3x3 taps
  constexpr int NT   = NT1 + nch2;              // + c1 taps (1 per group)

  // XCD-locality decode: g = XCD, owns 16 consecutive h for all (b, o-tile)
  const int gx = blockIdx.x & 7;
  const int r  = blockIdx.x >> 3;               // 0..127
  const int bo = r >> 4;                        // b*2 + o
  const int h  = gx * 16 + (r & 15);
  const int o_base = (bo & 1) * 128;
  const int b  = bo >> 1;

  const int tid  = threadIdx.x;
  const int lane = tid & 63;
  const int wid  = tid >> 6;
  const int m0 = (wid >> 1) * 64;
  const int n0 = (wid & 1) * 64;

  f32x4 acc[4][4];
  #pragma unroll
  for (int i = 0; i < 4; ++i)
    #pragma unroll
    for (int j = 0; j < 4; ++j) acc[i][j] = (f32x4){0.f, 0.f, 0.f, 0.f};

  // B staging lane constants: boff in 16KB pixel area; LDS row = pixel+1.
  // stored slot (o>>4) at row r holds source k-slot (o>>4)^(r&7).
  int ro1[4], ro2[4];
  #pragma unroll
  for (int s = 0; s < 4; ++s) {
    const int boff = (wid * 4 + s) * 1024 + lane * 16;
    const int p    = boff >> 7;                 // pixel 0..127
    const int koff = ((((boff >> 4) & 7) ^ ((p + 1) & 7)) << 3);
    ro1[s] = p * CIN1 + koff;
    ro2[s] = (CIN2 > 0) ? p * CIN2 + koff : 0;
  }
  const size_t B1base = (size_t)b * NPIX * CIN1;
  const size_t B2base = (CIN2 > 0) ? (size_t)b * NPIX * CIN2 : 0;

  auto stageA = [&](int tA, int buf) {
    char* dst = ldsbuf + buf * 16384;
    const char* wsrc = (const char*)(wR + ((size_t)tA * 256 + o_base) * 64);
    #pragma unroll
    for (int s = 0; s < 4; ++s)
      GLOAD16(wsrc + s * 4096 + tid * 16, dst + s * 4096 + tid * 16);
  };

  auto stageB = [&](int gg, int buf) {
    char* dst = ldsbuf + 32768 + buf * 16640 + 128;   // rows 1..128
    if (CIN2 == 0 || gg < NG1) {
      const int dy = gg / nch1, ch = gg - dy * nch1;
      const int hy = h + dy - 1;
      const bool oob = (hy < 0) | (hy >= HH);
      const ushort* bch = B1 + B1base + (size_t)(hy * WW) * CIN1 + ch * 64;
      #pragma unroll
      for (int s = 0; s < 4; ++s) {
        const ushort* src = oob ? zerop : (bch + ro1[s]);
        GLOAD16(src, dst + (wid * 4 + s) * 1024 + lane * 16);
      }
    } else {
      const int ch = gg - NG1;
      const ushort* bch = B2 + B2base + (size_t)(h * WW) * CIN2 + ch * 64;
      #pragma unroll
      for (int s = 0; s < 4; ++s)
        GLOAD16(bch + ro2[s], dst + (wid * 4 + s) * 1024 + lane * 16);
    }
  };

  // tap i -> (group, dx, A-tile index)
  auto g_of = [&](int i) -> int {
    return (CIN2 == 0 || i < NT1) ? i / 3 : NG1 + (i - NT1);
  };
  auto tA_of = [&](int i) -> int {
    if (CIN2 == 0 || i < NT1) {
      const int gg = i / 3, dxi = i - gg * 3;
      const int dy = gg / nch1, ch = gg - dy * nch1;
      return (dy * 3 + dxi) * nch1 + ch;
    }
    return i;                                    // c1 tiles follow at cb=NT1
  };

  // zero the 4 halo rows (rows 0 & 129 of both B buffers), once
  if (tid < 32) {
    const int buf = tid >> 4;
    const int k   = tid & 15;
    const int row = (k >> 3) ? 129 : 0;
    char* hz = ldsbuf + 32768 + buf * 16640 + row * 128 + (k & 7) * 16;
    us8 z = (us8){0,0,0,0,0,0,0,0};
    *(us8*)hz = z;
  }
  __syncthreads();

  stageB(0, 0);
  stageA(tA_of(0), 0);                           // 8 loads in flight
  for (int i = 0; i < NT; ++i) {
    asm volatile("s_waitcnt vmcnt(0)" ::: "memory"); // tap i data landed
    __builtin_amdgcn_s_barrier();
    __builtin_amdgcn_sched_barrier(0);
    const int gg = g_of(i);
    const int dx = (CIN2 == 0 || i < NT1) ? (i - (i / 3) * 3) - 1 : 0;
    if (i + 1 < NT) {
      stageA(tA_of(i + 1), (i + 1) & 1);
      const int gn = g_of(i + 1);
      if (gn != gg) stageB(gn, gn & 1);
    }
    const char* Ab = ldsbuf + (i & 1) * 16384;
    const char* Bb = ldsbuf + 32768 + (gg & 1) * 16640;
    bfrag af[2][4], bfv[2][4];
    #pragma unroll
    for (int kc = 0; kc < 2; ++kc) {
      const int swa = ((((kc << 2) | (lane >> 4)) ^ (lane & 7)) << 4);
      #pragma unroll
      for (int mf = 0; mf < 4; ++mf)
        af[kc][mf] = *(const bfrag*)(Ab + (m0 + mf * 16 + (lane & 15)) * 128 + swa);
      #pragma unroll
      for (int nf = 0; nf < 4; ++nf) {
        const int row = n0 + nf * 16 + (lane & 15) + 1 + dx;
        const int swb = ((((kc << 2) | (lane >> 4)) ^ (row & 7)) << 4);
        bfv[kc][nf] = *(const bfrag*)(Bb + row * 128 + swb);
      }
    }
    __builtin_amdgcn_s_setprio(1);
    #pragma unroll
    for (int kc = 0; kc < 2; ++kc)
      #pragma unroll
      for (int mf = 0; mf < 4; ++mf)
        #pragma unroll
        for (int nf = 0; nf < 4; ++nf)
          acc[mf][nf] = __builtin_amdgcn_mfma_f32_16x16x32_bf16(
              af[kc][mf], bfv[kc][nf], acc[mf][nf], 0, 0, 0);
    __builtin_amdgcn_s_setprio(0);
  }

  if (EPI == 4) {
    // dual bias + relu, transpose via LDS, store bf16 [b][p][256] rows
    __syncthreads();                             // all compute done, LDS free
    ushort* ct = (ushort*)ldsbuf;                // [128 px][136] (pad 8)
    const int pl0 = n0 + (lane & 15);
    #pragma unroll
    for (int mf = 0; mf < 4; ++mf) {
      #pragma unroll
      for (int r2 = 0; r2 < 4; ++r2) {
        const int ol = m0 + mf * 16 + (lane >> 4) * 4 + r2;
        const int o  = o_base + ol;
        const float bias = tb[o] + tb2[o];
        #pragma unroll
        for (int nf = 0; nf < 4; ++nf)
          ct[(pl0 + nf * 16) * 136 + ol] =
              f2bf(fmaxf(acc[mf][nf][r2] + bias, 0.f));
      }
    }
    __syncthreads();
    const int p  = tid >> 1;
    const int hf = tid & 1;
    ushort* dst = (ushort*)outp +
                  ((size_t)b * NPIX + h * WW + p) * 256 + o_base + hf * 64;
    const ushort* src = ct + p * 136 + hf * 64;
    #pragma unroll
    for (int j = 0; j < 8; ++j)
      *(us8*)(dst + j * 8) = *(const us8*)(src + j * 8);
    return;
  }

  // EPI 0 / 3: C row = o (coalesced over p within 16-lane groups)
  const int pc0 = h * WW + n0 + (lane & 15);
  #pragma unroll
  for (int mf = 0; mf < 4; ++mf) {
    #pragma unroll
    for (int r2 = 0; r2 < 4; ++r2) {
      const int o = o_base + m0 + mf * 16 + (lane >> 4) * 4 + r2;
      const float bias = tb[o];
      #pragma unroll
      for (int nf = 0; nf < 4; ++nf) {
        const int p = pc0 + nf * 16;
        float v = fmaxf(acc[mf][nf][r2] + bias, 0.f);
        const size_t oi = ((size_t)(b * 256 + o)) * NPIX + p;
        if (EPI == 0) ((ushort*)outp)[oi] = f2bf(v);
        else          ((float*)outp)[oi] = v;
      }
    }
  }
}

// ---------------------------------------------------------------------------
// fused weight repack: fold BN scale, bf16, swizzled LDS-image layout; emit tb.
// W is OIHW flat [COUT_local][CIN][TAPS]; tiles laid out cb + tap*nch + ch.
// ---------------------------------------------------------------------------
struct WSeg {
  const float *W, *g, *bb, *mm, *vv;
  ushort* dst; float* tb;
  int CIN, COUT, TAPS, o_off, cb, start, end;
};

__device__ __forceinline__ void wrepack_one(const WSeg& s, int e) {
  const int tap = e % s.TAPS;
  const int ci  = (e / s.TAPS) % s.CIN;
  const int o   = e / (s.TAPS * s.CIN);
  const int oi  = o + s.o_off;
  const float sc = s.g[o] * rsqrtf(s.vv[o] + EPSV);
  const int nch = s.CIN / 64;
  const int ch = ci >> 6, kl = ci & 63;
  const int slot = (kl >> 3) ^ (oi & 7);
  s.dst[(((size_t)((s.cb + tap * nch + ch) * s.COUT) + oi) << 6) +
        (slot << 3) + (kl & 7)] = f2bf(s.W[e] * sc);
  if (ci == 0 && tap == 0) s.tb[oi] = s.bb[o] - s.mm[o] * sc;
}

__global__ __launch_bounds__(256)
void wrepack_all(WSeg s0, WSeg s1, WSeg s2, WSeg s3, WSeg s4) {
  const int id = blockIdx.x * 256 + threadIdx.x;
  if (id < s0.end)      wrepack_one(s0, id - s0.start);
  else if (id < s1.end) wrepack_one(s1, id - s1.start);
  else if (id < s2.end) wrepack_one(s2, id - s2.start);
  else if (id < s3.end) wrepack_one(s3, id - s3.start);
  else if (id < s4.end) wrepack_one(s4, id - s4.start);
}

// ---------------------------------------------------------------------------
// x (fp32 NCHW) -> xT (bf16 [b][p][256]).  Thread = 4 px x 64 ch.
// ---------------------------------------------------------------------------
__global__ __launch_bounds__(256)
void repack_x(const float* __restrict__ x, ushort* __restrict__ xT)
{
  const int b  = blockIdx.z;
  const int cq = threadIdx.x >> 6;            // channel quarter
  const int pg = threadIdx.x & 63;
  const int p0 = blockIdx.x * 256 + pg * 4;
  const size_t xb = (size_t)b * 256 * NPIX;
  ushort* ob = xT + ((size_t)b * NPIX + p0) * 256 + cq * 64;
  for (int cc = 0; cc < 64; cc += 8) {
    us8 v[4];
    #pragma unroll
    for (int j = 0; j < 8; ++j) {
      const float4 q = *(const float4*)&x[xb + (size_t)(cq * 64 + cc + j) * NPIX + p0];
      v[0][j] = f2bf(q.x); v[1][j] = f2bf(q.y);
      v[2][j] = f2bf(q.z); v[3][j] = f2bf(q.w);
    }
    #pragma unroll
    for (int k = 0; k < 4; ++k)
      *(us8*)(ob + (size_t)k * 256 + cc) = v[k];
  }
}

// ---------------------------------------------------------------------------
// k1: top pool on transposed p12T.  Block (b, w-pair), 256 thr = 2 cols x 128c.
// Reverse cummax over h of c-half 0; unroll-8 prefetch hides load latency.
// topT[b][p][128] out.
// ---------------------------------------------------------------------------
__global__ __launch_bounds__(256)
void scan_top(const ushort* __restrict__ p12T, ushort* __restrict__ topT)
{
  const int b = blockIdx.x >> 6;
  const int w = (blockIdx.x & 63) * 2 + (threadIdx.x >> 7);
  const int c = threadIdx.x & 127;
  const size_t ib = (size_t)b * NPIX;
  float cur = -3.4e38f;
  for (int h8 = HH - 8; h8 >= 0; h8 -= 8) {
    float v[8];
    #pragma unroll
    for (int j = 0; j < 8; ++j)
      v[j] = bf2f(p12T[(ib + (size_t)(h8 + j) * WW + w) * 256 + c]);
    #pragma unroll
    for (int j = 7; j >= 0; --j) {
      cur = fmaxf(cur, v[j]);
      topT[(ib + (size_t)(h8 + j) * WW + w) * 128 + c] = f2bf(cur);
    }
  }
}

// ---------------------------------------------------------------------------
// k2: left pool + sum.  Block (b, h-pair), 256 thr = 2 rows x 128c.
// Reverse cummax over w of c-half 1 of p12T, add topT, write sumT[b][p][128].
// ---------------------------------------------------------------------------
__global__ __launch_bounds__(256)
void scan_left_sum(const ushort* __restrict__ p12T,
                   const ushort* __restrict__ topT,
                   ushort* __restrict__ sumT)
{
  const int b = blockIdx.x >> 6;
  const int h = (blockIdx.x & 63) * 2 + (threadIdx.x >> 7);
  const int c = threadIdx.x & 127;
  const size_t ib = (size_t)b * NPIX + (size_t)h * WW;
  float cur = -3.4e38f;
  for (int w8 = WW - 8; w8 >= 0; w8 -= 8) {
    float v[8], tv[8];
    #pragma unroll
    for (int j = 0; j < 8; ++j) {
      v[j]  = bf2f(p12T[(ib + w8 + j) * 256 + 128 + c]);
      tv[j] = bf2f(topT[(ib + w8 + j) * 128 + c]);
    }
    #pragma unroll
    for (int j = 7; j >= 0; --j) {
      cur = fmaxf(cur, v[j]);
      sumT[(ib + w8 + j) * 128 + c] = f2bf(cur + tv[j]);
    }
  }
}

// ---------------------------------------------------------------------------
extern "C" void kernel_launch(void* const* d_in, const int* in_sizes, int n_in,
                              void* d_out, int out_size, void* d_ws, size_t ws_size,
                              hipStream_t stream) {
  const float* x    = (const float*)d_in[0];
  const float* w_p1 = (const float*)d_in[1];
  const float* g_p1 = (const float*)d_in[2];
  const float* b_p1 = (const float*)d_in[3];
  const float* m_p1 = (const float*)d_in[4];
  const float* v_p1 = (const float*)d_in[5];
  const float* w_p2 = (const float*)d_in[6];
  const float* g_p2 = (const float*)d_in[7];
  const float* b_p2 = (const float*)d_in[8];
  const float* m_p2 = (const float*)d_in[9];
  const float* v_p2 = (const float*)d_in[10];
  const float* w_pc = (const float*)d_in[11];
  const float* g_pb = (const float*)d_in[12];
  const float* b_pb = (const float*)d_in[13];
  const float* m_pb = (const float*)d_in[14];
  const float* v_pb = (const float*)d_in[15];
  const float* w_c1 = (const float*)d_in[16];
  const float* g_b1 = (const float*)d_in[17];
  const float* b_b1 = (const float*)d_in[18];
  const float* m_b1 = (const float*)d_in[19];
  const float* v_b1 = (const float*)d_in[20];
  const float* w_c2 = (const float*)d_in[21];
  const float* g_c2 = (const float*)d_in[22];
  const float* b_c2 = (const float*)d_in[23];
  const float* m_c2 = (const float*)d_in[24];
  const float* v_c2 = (const float*)d_in[25];

  char* ws = (char*)d_ws;
  // arena (bytes):
  ushort* xT      = (ushort*)(ws + 0);           // 32MB [b][p][256]
  ushort* p12T    = (ushort*)(ws + 33554432);    // 32MB [b][p][256] transposed
  ushort* relu1T  = (ushort*)(ws + 33554432);    // 32MB alias p12T (dead)
  ushort* sumT    = (ushort*)(ws + 67108864);    // 16MB [b][p][128]
  ushort* topT    = (ushort*)(ws + 83886080);    // 16MB [b][p][128]
  ushort* wR_p12  = (ushort*)(ws + 100663296);   // 36 tiles  (1179648 B)
  ushort* wR_pcc1 = (ushort*)(ws + 101842944);   // 22 tiles  (720896 B)
  ushort* wR_c2   = (ushort*)(ws + 102563840);   // 36 tiles  (1179648 B)
  float*  tb_p12  = (float*)(ws + 103743488);    // 1KB each
  float*  tb_pc   = (float*)(ws + 103744512);
  float*  tb_c1   = (float*)(ws + 103745536);
  float*  tb_c2   = (float*)(ws + 103746560);
  ushort* zerop   = (ushort*)(ws + 103747584);   // 256B zeros
  float*  tb_zero = (float*)(ws + 103747840);    // 1KB zero biases

  hipMemsetAsync(zerop, 0, 256 + 1024, stream);  // zerop + tb_zero

  // fused weight repack (fold BN scale; emit tb)
  const int n_p  = 128 * 256 * 9;    // 294912 (p1 and p2 each)
  const int n_pc = 256 * 128 * 9;    // 294912
  const int n_c1 = 256 * 256 * 1;    // 65536
  const int n_c2 = 256 * 256 * 9;    // 589824
  WSeg s0 = {w_p1, g_p1, b_p1, m_p1, v_p1, wR_p12, tb_p12, 256, 256, 9, 0, 0,
             0, n_p};
  WSeg s1 = {w_p2, g_p2, b_p2, m_p2, v_p2, wR_p12, tb_p12, 256, 256, 9, 128, 0,
             n_p, 2 * n_p};
  WSeg s2 = {w_pc, g_pb, b_pb, m_pb, v_pb, wR_pcc1, tb_pc, 128, 256, 9, 0, 0,
             2 * n_p, 2 * n_p + n_pc};
  WSeg s3 = {w_c1, g_b1, b_b1, m_b1, v_b1, wR_pcc1, tb_c1, 256, 256, 1, 0, 18,
             2 * n_p + n_pc, 2 * n_p + n_pc + n_c1};
  WSeg s4 = {w_c2, g_c2, b_c2, m_c2, v_c2, wR_c2, tb_c2, 256, 256, 9, 0, 0,
             2 * n_p + n_pc + n_c1, 2 * n_p + n_pc + n_c1 + n_c2};
  const int n_all = 2 * n_p + n_pc + n_c1 + n_c2;
  wrepack_all<<<dim3((n_all + 255) / 256), 256, 0, stream>>>(s0, s1, s2, s3, s4);

  // x -> xT
  repack_x<<<dim3(NPIX / 256, 1, BB), 256, 0, stream>>>(x, xT);

  // p12T = relu(bn(conv3x3(x, [w_p1;w_p2]))), TRANSPOSED bf16 [b][p][256]
  convgemm<256, 9, 0, 0, 4><<<dim3(1024), 256, 0, stream>>>(
      xT, nullptr, wR_p12, tb_p12, tb_zero, p12T, zerop);

  // top pool (c 0-127) -> topT; left pool (c 128-255) + sum -> sumT
  scan_top<<<dim3(BB * 64), 256, 0, stream>>>(p12T, topT);
  scan_left_sum<<<dim3(BB * 64), 256, 0, stream>>>(p12T, topT, sumT);

  // relu1T = relu(bn(conv3x3(sumT)) + bn(conv1x1(x))), bf16 [b][p][256]
  // (fused pc + c1; writes transposed directly; overwrites p12T region)
  convgemm<128, 9, 256, 1, 4><<<dim3(1024), 256, 0, stream>>>(
      sumT, xT, wR_pcc1, tb_pc, tb_c1, relu1T, zerop);

  // out = relu(bn(conv3x3(relu1T))), fp32 NCHW
  convgemm<256, 9, 0, 0, 3><<<dim3(1024), 256, 0, stream>>>(
      relu1T, nullptr, wR_c2, tb_c2, nullptr, (void*)d_out, zerop);
}